// Round 1
// baseline (549.027 us; speedup 1.0000x reference)
//
#include <hip/hip_runtime.h>
#include <math.h>

#define NN 30000
#define EE 480000
#define BB 64

// ---------------- wave helpers ----------------
__device__ __forceinline__ float wsum64(float v){
  #pragma unroll
  for (int m = 32; m >= 1; m >>= 1) v += __shfl_xor(v, m, 64);
  return v;
}
__device__ __forceinline__ float wmax64(float v){
  #pragma unroll
  for (int m = 32; m >= 1; m >>= 1) v = fmaxf(v, __shfl_xor(v, m, 64));
  return v;
}
__device__ __forceinline__ float wsum16(float v){
  #pragma unroll
  for (int m = 1; m < 16; m <<= 1) v += __shfl_xor(v, m, 64);
  return v;
}

// ---------------- CSR build ----------------
__global__ void hist_kernel(const int* __restrict__ dst, int* __restrict__ deg){
  int e = blockIdx.x*256 + threadIdx.x;
  if (e < EE) atomicAdd(&deg[dst[e]], 1);
}

__global__ __launch_bounds__(1024) void scan_kernel(const int* __restrict__ deg, int* __restrict__ rowptr){
  __shared__ int s[1024];
  int tid = threadIdx.x;
  const int PER = 30;                       // 1024*30 >= 30000
  int base = tid * PER;
  int sum = 0;
  for (int j = 0; j < PER; j++){ int idx = base+j; if (idx < NN) sum += deg[idx]; }
  s[tid] = sum; __syncthreads();
  for (int off = 1; off < 1024; off <<= 1){
    int v = 0;
    if (tid >= off) v = s[tid-off];
    __syncthreads();
    s[tid] += v;
    __syncthreads();
  }
  int run = s[tid] - sum;                   // exclusive prefix
  for (int j = 0; j < PER; j++){
    int idx = base+j;
    if (idx < NN){ rowptr[idx] = run; run += deg[idx]; }
  }
  if (tid == 1023) rowptr[NN] = s[1023];
}

__global__ void scatter_kernel(const int* __restrict__ src, const int* __restrict__ dst,
    const int* __restrict__ rowptr, int* __restrict__ cursor,
    int* __restrict__ slot_e, int* __restrict__ srccsr){
  int e = blockIdx.x*256 + threadIdx.x;
  if (e >= EE) return;
  int d = dst[e];
  int slot = rowptr[d] + atomicAdd(&cursor[d], 1);
  slot_e[e] = slot;
  srccsr[slot] = src[e];
}

// ---------------- edge-logit precompute: wae[h][k] = sum_f We[k][h*64+f]*ae[h][f] ----------------
template<int H>
__global__ void wae_kernel(const float* __restrict__ We, const float* __restrict__ ae, float* __restrict__ wae){
  int t = threadIdx.x;
  if (t >= 32*H) return;
  int h = t >> 5, k = t & 31;
  float s = 0.f;
  for (int f = 0; f < 64; f++) s += We[k*(64*H) + h*64 + f] * ae[h*64 + f];
  wae[h*32 + k] = s;
}

// edot_csr[slot][h] = ea[e] . wae[h]   (written in CSR slot order)
template<int H>
__global__ __launch_bounds__(256) void edot_kernel(const float* __restrict__ ea, const float* __restrict__ wae,
    const int* __restrict__ slot_e, float* __restrict__ edot){
  __shared__ float s_wae[32*H];
  if (threadIdx.x < 32*H) s_wae[threadIdx.x] = wae[threadIdx.x];
  __syncthreads();
  int e = blockIdx.x*256 + threadIdx.x;
  if (e >= EE) return;
  const float4* row = (const float4*)(ea + (size_t)e*32);
  float4 r[8];
  #pragma unroll
  for (int q = 0; q < 8; q++) r[q] = row[q];
  const float4* wv = (const float4*)s_wae;
  float dots[H];
  #pragma unroll
  for (int h = 0; h < H; h++){
    float s = 0.f;
    #pragma unroll
    for (int q = 0; q < 8; q++){
      float4 w = wv[h*8 + q];
      s += r[q].x*w.x + r[q].y*w.y + r[q].z*w.z + r[q].w*w.w;
    }
    dots[h] = s;
  }
  int slot = slot_e[e];
  if constexpr (H == 4){
    float4 o; o.x = dots[0]; o.y = dots[1]; o.z = dots[2]; o.w = dots[3];
    *(float4*)(edot + (size_t)slot*4) = o;
  } else {
    edot[slot] = dots[0];
  }
}

// ---------------- tiled SGEMM: out[M,NCOL] = A[M,K_] @ W[K_,NCOL], optional fused BN+ReLU on A ----------------
template<int K_, int NCOL, bool NORM>
__global__ __launch_bounds__(256) void gemm_kernel(const float* __restrict__ A,
    const float* __restrict__ W, const float* __restrict__ scale,
    const float* __restrict__ shift, float* __restrict__ out){
  __shared__ float As[16][68];   // [kk][row], pad 68 -> 2-way-max bank aliasing, 16B-aligned rows
  __shared__ float Ws[16][64];   // [kk][col]
  const int tid = threadIdx.x;
  const int row0 = blockIdx.x * 64;
  const int col0 = blockIdx.y * 64;
  const int tx = tid & 15, ty = tid >> 4;        // micro-tile: rows ty*4.., cols tx*4..
  const int la_k = tid & 15, la_r = tid >> 4;
  const int lw_c = tid & 63, lw_k = tid >> 6;
  float acc[4][4] = {};
  for (int k0 = 0; k0 < K_; k0 += 16){
    #pragma unroll
    for (int i = 0; i < 4; i++){
      int r = la_r + 16*i;
      int grow = row0 + r;
      float v = 0.f;
      if (grow < NN) v = A[(size_t)grow*K_ + k0 + la_k];
      if constexpr (NORM) v = fmaxf(fmaf(v, scale[k0+la_k], shift[k0+la_k]), 0.f);
      As[la_k][r] = v;
    }
    #pragma unroll
    for (int i = 0; i < 4; i++){
      int kk = lw_k + 4*i;
      Ws[kk][lw_c] = W[(size_t)(k0+kk)*NCOL + col0 + lw_c];
    }
    __syncthreads();
    #pragma unroll
    for (int kk = 0; kk < 16; kk++){
      float4 a = *(const float4*)&As[kk][ty*4];
      float4 w = *(const float4*)&Ws[kk][tx*4];
      float av[4] = {a.x, a.y, a.z, a.w};
      float wv[4] = {w.x, w.y, w.z, w.w};
      #pragma unroll
      for (int ii = 0; ii < 4; ii++)
        #pragma unroll
        for (int jj = 0; jj < 4; jj++)
          acc[ii][jj] = fmaf(av[ii], wv[jj], acc[ii][jj]);
    }
    __syncthreads();
  }
  #pragma unroll
  for (int i = 0; i < 4; i++){
    int grow = row0 + ty*4 + i;
    if (grow < NN){
      float4 o; o.x = acc[i][0]; o.y = acc[i][1]; o.z = acc[i][2]; o.w = acc[i][3];
      *(float4*)(out + (size_t)grow*NCOL + col0 + tx*4) = o;
    }
  }
}

// ---------------- per-node attention logits al_src/al_dst ----------------
__global__ __launch_bounds__(256) void al_kernel_h4(const float* __restrict__ xs, const float* __restrict__ as_,
    const float* __restrict__ ad_, float* __restrict__ alsrc, float* __restrict__ aldst){
  int wid = threadIdx.x >> 6, lane = threadIdx.x & 63;
  int n = blockIdx.x*4 + wid;
  float4 v = *(const float4*)(xs + (size_t)n*256 + 4*lane);
  float4 a = *(const float4*)(as_ + 4*lane);
  float4 d = *(const float4*)(ad_ + 4*lane);
  float ps = v.x*a.x + v.y*a.y + v.z*a.z + v.w*a.w;
  float pd = v.x*d.x + v.y*d.y + v.z*d.z + v.w*d.w;
  ps = wsum16(ps); pd = wsum16(pd);      // reduce inside each head's 16-lane group
  if ((lane & 15) == 0){ alsrc[n*4 + (lane>>4)] = ps; aldst[n*4 + (lane>>4)] = pd; }
}

__global__ __launch_bounds__(256) void al_kernel_h1(const float* __restrict__ xs, const float* __restrict__ as_,
    const float* __restrict__ ad_, float* __restrict__ alsrc, float* __restrict__ aldst){
  int wid = threadIdx.x >> 6, lane = threadIdx.x & 63;
  int n = blockIdx.x*4 + wid;
  float v = xs[(size_t)n*64 + lane];
  float ps = wsum64(v*as_[lane]);
  float pd = wsum64(v*ad_[lane]);
  if (lane == 0){ alsrc[n] = ps; aldst[n] = pd; }
}

// ---------------- the big one: per-dst segment softmax + weighted gather, one wave per node ----------------
// Self loop handled virtually: its edge-logit = mean of incoming edot (linearity of the dot).
template<int H>
__global__ __launch_bounds__(64) void agg_kernel(const int* __restrict__ rowptr,
    const int* __restrict__ src_csr, const float* __restrict__ edot,
    const float* __restrict__ al_src, const float* __restrict__ al_dst,
    const float* __restrict__ xs, const float* __restrict__ bias,
    float* __restrict__ out){
  constexpr int CH = 128;
  __shared__ float s_e[CH*H];
  __shared__ int s_src[CH];
  const int i = blockIdx.x;
  const int lane = threadIdx.x;
  const int r0 = rowptr[i];
  const int d  = rowptr[i+1] - r0;
  float ad[H], asi[H];
  #pragma unroll
  for (int h = 0; h < H; h++){ ad[h] = al_dst[i*H+h]; asi[h] = al_src[i*H+h]; }
  // pass 0: mean edot over incoming -> self-loop edge logit
  float se[H];
  #pragma unroll
  for (int h = 0; h < H; h++) se[h] = 0.f;
  for (int t = lane; t < d; t += 64){
    if constexpr (H == 4){
      float4 ev = *(const float4*)(edot + (size_t)(r0+t)*4);
      se[0]+=ev.x; se[1]+=ev.y; se[2]+=ev.z; se[3]+=ev.w;
    } else se[0] += edot[r0+t];
  }
  float invd = 1.f / (float)(d > 0 ? d : 1);
  #pragma unroll
  for (int h = 0; h < H; h++) se[h] = wsum64(se[h]) * invd;
  float sa[H], m[H];
  #pragma unroll
  for (int h = 0; h < H; h++){ float a = asi[h]+ad[h]+se[h]; sa[h] = a > 0.f ? a : 0.2f*a; m[h] = sa[h]; }
  // pass 1: alphas (cache first CH in LDS) + running max
  for (int t = lane; t < d; t += 64){
    int s = r0 + t;
    int sn = src_csr[s];
    if (t < CH) s_src[t] = sn;
    float al[H];
    if constexpr (H == 4){
      float4 av = *(const float4*)(al_src + (size_t)sn*4);
      float4 ev = *(const float4*)(edot + (size_t)s*4);
      al[0]=av.x+ad[0]+ev.x; al[1]=av.y+ad[1]+ev.y; al[2]=av.z+ad[2]+ev.z; al[3]=av.w+ad[3]+ev.w;
    } else {
      al[0] = al_src[sn] + ad[0] + edot[s];
    }
    #pragma unroll
    for (int h = 0; h < H; h++){
      float a = al[h]; a = a > 0.f ? a : 0.2f*a;
      if (t < CH) s_e[t*H+h] = a;
      m[h] = fmaxf(m[h], a);
    }
  }
  #pragma unroll
  for (int h = 0; h < H; h++) m[h] = wmax64(m[h]);
  // pass 2: unnormalized exp-weighted gather, chunked through LDS
  float acc[H];
  #pragma unroll
  for (int j = 0; j < H; j++) acc[j] = 0.f;
  float dpart[H];
  #pragma unroll
  for (int h = 0; h < H; h++) dpart[h] = 0.f;
  int c0 = 0;
  while (c0 < d){
    int cl = min(CH, d - c0);
    if (c0 > 0){                            // rare: degree > 128, reload LDS
      __syncthreads();
      for (int t = lane; t < cl; t += 64){
        int s = r0 + c0 + t;
        int sn = src_csr[s];
        s_src[t] = sn;
        if constexpr (H == 4){
          float4 av = *(const float4*)(al_src + (size_t)sn*4);
          float4 ev = *(const float4*)(edot + (size_t)s*4);
          float a0=av.x+ad[0]+ev.x, a1=av.y+ad[1]+ev.y, a2=av.z+ad[2]+ev.z, a3=av.w+ad[3]+ev.w;
          s_e[t*4+0]=a0>0.f?a0:0.2f*a0; s_e[t*4+1]=a1>0.f?a1:0.2f*a1;
          s_e[t*4+2]=a2>0.f?a2:0.2f*a2; s_e[t*4+3]=a3>0.f?a3:0.2f*a3;
        } else {
          float a = al_src[sn] + ad[0] + edot[s];
          s_e[t] = a > 0.f ? a : 0.2f*a;
        }
      }
    }
    for (int t = lane; t < cl; t += 64){     // same-lane RAW into LDS, no barrier needed
      #pragma unroll
      for (int h = 0; h < H; h++){
        float e = __expf(s_e[t*H+h] - m[h]);
        s_e[t*H+h] = e;
        dpart[h] += e;
      }
    }
    __syncthreads();
    if constexpr (H == 4){
      const int head = lane >> 4;
      for (int t = 0; t < cl; t++){
        int sn = s_src[t];
        float w = s_e[t*4 + head];
        float4 r = *(const float4*)(xs + (size_t)sn*256 + 4*lane);  // 1KB coalesced per wave
        acc[0] += w*r.x; acc[1] += w*r.y; acc[2] += w*r.z; acc[3] += w*r.w;
      }
    } else {
      for (int t = 0; t < cl; t++){
        acc[0] += s_e[t] * xs[(size_t)s_src[t]*64 + lane];
      }
    }
    c0 += CH;
  }
  // self loop contribution
  float es[H];
  #pragma unroll
  for (int h = 0; h < H; h++) es[h] = __expf(sa[h] - m[h]);
  if (lane == 0){
    #pragma unroll
    for (int h = 0; h < H; h++) dpart[h] += es[h];
  }
  if constexpr (H == 4){
    const int head = lane >> 4;
    float4 r = *(const float4*)(xs + (size_t)i*256 + 4*lane);
    float w = es[head];
    acc[0] += w*r.x; acc[1] += w*r.y; acc[2] += w*r.z; acc[3] += w*r.w;
  } else {
    acc[0] += es[0] * xs[(size_t)i*64 + lane];
  }
  float denom[H];
  #pragma unroll
  for (int h = 0; h < H; h++) denom[h] = wsum64(dpart[h]);
  if constexpr (H == 4){
    const int head = lane >> 4;
    float inv = 1.f / denom[head];
    float4 bv = *(const float4*)(bias + 4*lane);
    float4 o;
    o.x = acc[0]*inv + bv.x; o.y = acc[1]*inv + bv.y;
    o.z = acc[2]*inv + bv.z; o.w = acc[3]*inv + bv.w;
    *(float4*)(out + (size_t)i*256 + 4*lane) = o;
  } else {
    out[(size_t)i*64 + lane] = acc[0]/denom[0] + bias[lane];
  }
}

// ---------------- BN ----------------
template<int F>
__global__ __launch_bounds__(256) void bn_stats_kernel(const float* __restrict__ h,
    float* __restrict__ cs, float* __restrict__ csq){
  constexpr int RP = 256 / F;
  int col = threadIdx.x % F;
  int ro  = threadIdx.x / F;
  float s = 0.f, s2 = 0.f;
  for (int r = blockIdx.x*RP + ro; r < NN; r += 256*RP){
    float v = h[(size_t)r*F + col];
    s += v; s2 += v*v;
  }
  atomicAdd(&cs[col], s);
  atomicAdd(&csq[col], s2);
}

__global__ void bn_scale_kernel(const float* __restrict__ cs, const float* __restrict__ csq,
    const float* __restrict__ g, const float* __restrict__ b,
    float* __restrict__ scale, float* __restrict__ shift, int F){
  int f = threadIdx.x;
  if (f >= F) return;
  float mu  = cs[f]  * (1.f/NN);
  float var = csq[f] * (1.f/NN) - mu*mu;
  float rs  = rsqrtf(var + 1e-5f);
  float sc  = rs * g[f];
  scale[f] = sc;
  shift[f] = b[f] - mu*sc;
}

// ---------------- pooling ----------------
__global__ void gp_kernel(const int* __restrict__ batch, int* __restrict__ gp){
  int n = blockIdx.x*256 + threadIdx.x;
  if (n >= NN) return;
  int b = batch[n];
  if (n == 0){ for (int g = 0; g <= b; g++) gp[g] = 0; }
  else { int bp = batch[n-1]; for (int g = bp+1; g <= b; g++) gp[g] = n; }
  if (n == NN-1){ for (int g = b+1; g <= BB; g++) gp[g] = NN; }
}

__global__ __launch_bounds__(256) void gate_kernel(const float* __restrict__ h, const float* __restrict__ scale,
    const float* __restrict__ shift, const float* __restrict__ Wg, const float* __restrict__ bg,
    float* __restrict__ hn, float* __restrict__ gate){
  int wid = threadIdx.x >> 6, lane = threadIdx.x & 63;
  int n = blockIdx.x*4 + wid;
  float v = h[(size_t)n*64 + lane];
  float xx = fmaxf(fmaf(v, scale[lane], shift[lane]), 0.f);
  hn[(size_t)n*64 + lane] = xx;
  float p = wsum64(xx * Wg[lane]);
  if (lane == 0) gate[n] = p + bg[0];
}

__global__ __launch_bounds__(256) void pool_kernel(const int* __restrict__ gp, const float* __restrict__ gate,
    const float* __restrict__ hn, float* __restrict__ out){
  __shared__ float red[256];
  __shared__ float wred_[4];
  int b = blockIdx.x, tid = threadIdx.x;
  int s = gp[b], e = gp[b+1];
  if (e <= s){ if (tid < 64) out[b*64 + tid] = 0.f; return; }
  float mloc = -1e30f;
  for (int n = s + tid; n < e; n += 256) mloc = fmaxf(mloc, gate[n]);
  mloc = wmax64(mloc);
  if ((tid & 63) == 0) red[tid >> 6] = mloc;
  __syncthreads();
  float m = fmaxf(fmaxf(red[0], red[1]), fmaxf(red[2], red[3]));
  __syncthreads();
  int col = tid & 63, ro = tid >> 6;
  float acc = 0.f, wp = 0.f;
  for (int n = s + ro; n < e; n += 4){
    float w = __expf(gate[n] - m);
    if (col == 0) wp += w;
    acc += w * hn[(size_t)n*64 + col];
  }
  red[tid] = acc;
  if (col == 0) wred_[ro] = wp;
  __syncthreads();
  if (ro == 0){
    float tot = red[col] + red[64+col] + red[128+col] + red[192+col];
    float wsm = wred_[0] + wred_[1] + wred_[2] + wred_[3];
    out[b*64 + col] = tot / wsm;
  }
}

// ---------------- host ----------------
extern "C" void kernel_launch(void* const* d_in, const int* in_sizes, int n_in,
                              void* d_out, int out_size, void* d_ws, size_t ws_size,
                              hipStream_t stream){
  const float* x     = (const float*)d_in[0];
  const float* ea    = (const float*)d_in[1];
  const int*   ei    = (const int*)d_in[2];
  const int*   batch = (const int*)d_in[3];
  const float* W1    = (const float*)d_in[4];
  const float* We1   = (const float*)d_in[5];
  const float* as1   = (const float*)d_in[6];
  const float* ad1   = (const float*)d_in[7];
  const float* ae1   = (const float*)d_in[8];
  const float* bias1 = (const float*)d_in[9];
  const float* g1    = (const float*)d_in[10];
  const float* b1    = (const float*)d_in[11];
  const float* W2    = (const float*)d_in[12];
  const float* We2   = (const float*)d_in[13];
  const float* as2   = (const float*)d_in[14];
  const float* ad2   = (const float*)d_in[15];
  const float* ae2   = (const float*)d_in[16];
  const float* bias2 = (const float*)d_in[17];
  const float* g2    = (const float*)d_in[18];
  const float* b2    = (const float*)d_in[19];
  const float* Wg    = (const float*)d_in[20];
  const float* bg    = (const float*)d_in[21];
  const int* srcI = ei;
  const int* dstI = ei + EE;

  char* ws = (char*)d_ws;
  int*   deg    = (int*)(ws + 0);          // 120000 -> pad 120064
  int*   cursor = (int*)(ws + 120064);     // 120000 -> pad 120064
  float* stats  = (float*)(ws + 240128);   // 1024 floats: cs1@0 csq1@256 cs2@512 csq2@576
  int*   rowptr = (int*)(ws + 244224);     // (N+1) ints -> pad 120064
  int*   slot_e = (int*)(ws + 364288);     // E ints
  int*   srccsr = (int*)(ws + 2284288);    // E ints
  float* wae    = (float*)(ws + 4204288);  // 128 floats max
  float* ss     = (float*)(ws + 4204800);  // scale1@0 shift1@256 scale2@512 shift2@576
  float* alsrc  = (float*)(ws + 4208896);  // N*4 floats max
  float* aldst  = (float*)(ws + 4689152);
  int*   gp     = (int*)(ws + 5169408);    // B+1 ints
  float* gateb  = (float*)(ws + 5169920);  // N floats
  float* edotb  = (float*)(ws + 5289984);  // E*4 floats (layer2 reuses E floats)
  float* xsb    = (float*)(ws + 12969984); // 30000*256 floats (layer2 xs2 / hn reuse)
  float* hb     = (float*)(ws + 43689984); // 30000*256 floats (h1_raw then h2_raw)
  // total footprint ~74.4 MB

  (void)hipMemsetAsync(ws, 0, 244224, stream);   // deg, cursor, stats

  hist_kernel<<<1875, 256, 0, stream>>>(dstI, deg);
  scan_kernel<<<1, 1024, 0, stream>>>(deg, rowptr);
  scatter_kernel<<<1875, 256, 0, stream>>>(srcI, dstI, rowptr, cursor, slot_e, srccsr);

  // ---- layer 1 (H=4, F=256) ----
  wae_kernel<4><<<1, 128, 0, stream>>>(We1, ae1, wae);
  edot_kernel<4><<<1875, 256, 0, stream>>>(ea, wae, slot_e, edotb);
  gemm_kernel<128, 256, false><<<dim3(469, 4), 256, 0, stream>>>(x, W1, nullptr, nullptr, xsb);
  al_kernel_h4<<<7500, 256, 0, stream>>>(xsb, as1, ad1, alsrc, aldst);
  agg_kernel<4><<<30000, 64, 0, stream>>>(rowptr, srccsr, edotb, alsrc, aldst, xsb, bias1, hb);
  bn_stats_kernel<256><<<256, 256, 0, stream>>>(hb, stats + 0, stats + 256);
  bn_scale_kernel<<<1, 256, 0, stream>>>(stats + 0, stats + 256, g1, b1, ss + 0, ss + 256, 256);

  // ---- layer 2 (H=1, F=64), BN+ReLU fused into GEMM A-load ----
  gemm_kernel<256, 64, true><<<dim3(469, 1), 256, 0, stream>>>(hb, W2, ss + 0, ss + 256, xsb);
  al_kernel_h1<<<7500, 256, 0, stream>>>(xsb, as2, ad2, alsrc, aldst);
  wae_kernel<1><<<1, 32, 0, stream>>>(We2, ae2, wae);
  edot_kernel<1><<<1875, 256, 0, stream>>>(ea, wae, slot_e, edotb);
  agg_kernel<1><<<30000, 64, 0, stream>>>(rowptr, srccsr, edotb, alsrc, aldst, xsb, bias2, hb);
  bn_stats_kernel<64><<<256, 256, 0, stream>>>(hb, stats + 512, stats + 576);
  bn_scale_kernel<<<1, 256, 0, stream>>>(stats + 512, stats + 576, g2, b2, ss + 512, ss + 576, 64);

  // ---- pool ----
  gp_kernel<<<118, 256, 0, stream>>>(batch, gp);
  gate_kernel<<<7500, 256, 0, stream>>>(hb, ss + 512, ss + 576, Wg, bg, xsb /*hn*/, gateb);
  pool_kernel<<<64, 256, 0, stream>>>(gp, gateb, xsb, (float*)d_out);
}

// Round 2
// 506.861 us; speedup vs baseline: 1.0832x; 1.0832x over previous
//
#include <hip/hip_runtime.h>
#include <math.h>

#define NN 30000
#define EE 480000
#define BB 64

// ---------------- helpers ----------------
__device__ __forceinline__ float wsum64(float v){
  #pragma unroll
  for (int m = 32; m >= 1; m >>= 1) v += __shfl_xor(v, m, 64);
  return v;
}
__device__ __forceinline__ float wmax64(float v){
  #pragma unroll
  for (int m = 32; m >= 1; m >>= 1) v = fmaxf(v, __shfl_xor(v, m, 64));
  return v;
}
__device__ __forceinline__ float wsum16(float v){
  #pragma unroll
  for (int m = 1; m < 16; m <<= 1) v += __shfl_xor(v, m, 64);
  return v;
}
__device__ __forceinline__ unsigned short f2b(float f){   // fp32 -> bf16 RNE
  union { float f; unsigned u; } v; v.f = f;
  unsigned r = v.u + 0x7fffu + ((v.u >> 16) & 1u);
  return (unsigned short)(r >> 16);
}
__device__ __forceinline__ float b2f(unsigned short u){
  union { unsigned u; float f; } v; v.u = ((unsigned)u) << 16;
  return v.f;
}

// ---------------- CSR build ----------------
__global__ void hist_kernel(const int* __restrict__ dst, int* __restrict__ deg){
  int e = blockIdx.x*256 + threadIdx.x;
  if (e < EE) atomicAdd(&deg[dst[e]], 1);
}

__global__ __launch_bounds__(1024) void scan_kernel(const int* __restrict__ deg, int* __restrict__ rowptr){
  __shared__ int s[1024];
  int tid = threadIdx.x;
  const int PER = 30;
  int base = tid * PER;
  int sum = 0;
  for (int j = 0; j < PER; j++){ int idx = base+j; if (idx < NN) sum += deg[idx]; }
  s[tid] = sum; __syncthreads();
  for (int off = 1; off < 1024; off <<= 1){
    int v = 0;
    if (tid >= off) v = s[tid-off];
    __syncthreads();
    s[tid] += v;
    __syncthreads();
  }
  int run = s[tid] - sum;
  for (int j = 0; j < PER; j++){
    int idx = base+j;
    if (idx < NN){ rowptr[idx] = run; run += deg[idx]; }
  }
  if (tid == 1023) rowptr[NN] = s[1023];
}

__global__ void scatter_kernel(const int* __restrict__ src, const int* __restrict__ dst,
    const int* __restrict__ rowptr, int* __restrict__ cursor,
    int* __restrict__ slot_e, int* __restrict__ srccsr){
  int e = blockIdx.x*256 + threadIdx.x;
  if (e >= EE) return;
  int d = dst[e];
  int slot = rowptr[d] + atomicAdd(&cursor[d], 1);
  slot_e[e] = slot;
  srccsr[slot] = src[e];
}

// ---------------- wae precompute for BOTH layers ----------------
// wae[0..127]  : layer1, wae1[h][k] = sum_f We1[k][h*64+f]*ae1[h][f]
// wae[128..159]: layer2, wae2[k]    = sum_f We2[k][f]*ae2[f]
__global__ void wae_kernel(const float* __restrict__ We1, const float* __restrict__ ae1,
                           const float* __restrict__ We2, const float* __restrict__ ae2,
                           float* __restrict__ wae){
  int t = threadIdx.x;
  if (t < 128){
    int h = t >> 5, k = t & 31;
    float s = 0.f;
    for (int f = 0; f < 64; f++) s += We1[k*256 + h*64 + f] * ae1[h*64 + f];
    wae[h*32 + k] = s;
  } else if (t < 160){
    int k = t - 128;
    float s = 0.f;
    for (int f = 0; f < 64; f++) s += We2[k*64 + f] * ae2[f];
    wae[128 + k] = s;
  }
}

// one pass over ea: 5 dots per edge (4 layer-1 heads + 1 layer-2), written in CSR slot order
__global__ __launch_bounds__(256) void edot_kernel(const float* __restrict__ ea, const float* __restrict__ wae,
    const int* __restrict__ slot_e, float* __restrict__ edot1, float* __restrict__ edot2){
  __shared__ float s_w[160];
  if (threadIdx.x < 160) s_w[threadIdx.x] = wae[threadIdx.x];
  __syncthreads();
  int e = blockIdx.x*256 + threadIdx.x;
  if (e >= EE) return;
  const float4* row = (const float4*)(ea + (size_t)e*32);
  float4 r[8];
  #pragma unroll
  for (int q = 0; q < 8; q++) r[q] = row[q];
  const float4* wv = (const float4*)s_w;
  float dots[5];
  #pragma unroll
  for (int h = 0; h < 5; h++){
    float s = 0.f;
    #pragma unroll
    for (int q = 0; q < 8; q++){
      float4 w = wv[h*8 + q];
      s += r[q].x*w.x + r[q].y*w.y + r[q].z*w.z + r[q].w*w.w;
    }
    dots[h] = s;
  }
  int slot = slot_e[e];
  float4 o; o.x = dots[0]; o.y = dots[1]; o.z = dots[2]; o.w = dots[3];
  *(float4*)(edot1 + (size_t)slot*4) = o;
  edot2[slot] = dots[4];
}

// ---------------- SGEMM + fused BN/ReLU on A + fused al_src/al_dst + bf16 output ----------------
// out[M,NCOL]=A@W (bf16). blockIdx.y = head (NCOL per head = 64). Writes alsrc/aldst[row*HGRID+head].
template<int K_, int NCOL, bool NORM, int HGRID>
__global__ __launch_bounds__(256) void gemm_kernel(const float* __restrict__ A,
    const float* __restrict__ W, const float* __restrict__ scale,
    const float* __restrict__ shift, const float* __restrict__ a_s,
    const float* __restrict__ a_d,
    unsigned short* __restrict__ out, float* __restrict__ alsrc, float* __restrict__ aldst){
  __shared__ float As[16][68];
  __shared__ float Ws[16][64];
  const int tid = threadIdx.x;
  const int row0 = blockIdx.x * 64;
  const int head = blockIdx.y;
  const int col0 = head * 64;
  const int tx = tid & 15, ty = tid >> 4;
  const int la_k = tid & 15, la_r = tid >> 4;
  const int lw_c = tid & 63, lw_k = tid >> 6;
  float acc[4][4] = {};
  for (int k0 = 0; k0 < K_; k0 += 16){
    #pragma unroll
    for (int i = 0; i < 4; i++){
      int r = la_r + 16*i;
      int grow = row0 + r;
      float v = 0.f;
      if (grow < NN) v = A[(size_t)grow*K_ + k0 + la_k];
      if constexpr (NORM) v = fmaxf(fmaf(v, scale[k0+la_k], shift[k0+la_k]), 0.f);
      As[la_k][r] = v;
    }
    #pragma unroll
    for (int i = 0; i < 4; i++){
      int kk = lw_k + 4*i;
      Ws[kk][lw_c] = W[(size_t)(k0+kk)*NCOL + col0 + lw_c];
    }
    __syncthreads();
    #pragma unroll
    for (int kk = 0; kk < 16; kk++){
      float4 a = *(const float4*)&As[kk][ty*4];
      float4 w = *(const float4*)&Ws[kk][tx*4];
      float av[4] = {a.x, a.y, a.z, a.w};
      float wv[4] = {w.x, w.y, w.z, w.w};
      #pragma unroll
      for (int ii = 0; ii < 4; ii++)
        #pragma unroll
        for (int jj = 0; jj < 4; jj++)
          acc[ii][jj] = fmaf(av[ii], wv[jj], acc[ii][jj]);
    }
    __syncthreads();
  }
  // epilogue: al logits (per-head dot) + bf16 store
  float4 asv = *(const float4*)(a_s + head*64 + tx*4);
  float4 adv = *(const float4*)(a_d + head*64 + tx*4);
  #pragma unroll
  for (int i = 0; i < 4; i++){
    int grow = row0 + ty*4 + i;
    float ps = acc[i][0]*asv.x + acc[i][1]*asv.y + acc[i][2]*asv.z + acc[i][3]*asv.w;
    float pd = acc[i][0]*adv.x + acc[i][1]*adv.y + acc[i][2]*adv.z + acc[i][3]*adv.w;
    ps = wsum16(ps); pd = wsum16(pd);
    if (grow < NN){
      if (tx == 0){
        alsrc[(size_t)grow*HGRID + head] = ps;
        aldst[(size_t)grow*HGRID + head] = pd;
      }
      ushort4 o;
      o.x = f2b(acc[i][0]); o.y = f2b(acc[i][1]); o.z = f2b(acc[i][2]); o.w = f2b(acc[i][3]);
      *(ushort4*)(out + (size_t)grow*NCOL + col0 + tx*4) = o;
    }
  }
}

// ---------------- segment softmax + bf16 weighted gather: one wave per node, 4 nodes/block ----------------
template<int H>
__global__ __launch_bounds__(256) void agg_kernel(const int* __restrict__ rowptr,
    const int* __restrict__ src_csr, const float* __restrict__ edot,
    const float* __restrict__ al_src, const float* __restrict__ al_dst,
    const unsigned short* __restrict__ xsb, const float* __restrict__ bias,
    float* __restrict__ out){
  constexpr int CH = 128;
  __shared__ float s_e_all[4][CH*H];
  __shared__ int   s_src_all[4][CH];
  const int wid  = threadIdx.x >> 6;
  const int lane = threadIdx.x & 63;
  const int i = blockIdx.x*4 + wid;
  float* s_e  = s_e_all[wid];
  int*   s_src = s_src_all[wid];
  const int r0 = rowptr[i];
  const int d  = rowptr[i+1] - r0;
  float ad[H], asi[H];
  #pragma unroll
  for (int h = 0; h < H; h++){ ad[h] = al_dst[(size_t)i*H+h]; asi[h] = al_src[(size_t)i*H+h]; }
  // pass 1: leaky(alpha) per edge (cache first CH in LDS), running max + edot sum (for self loop)
  float sesum[H], m[H];
  #pragma unroll
  for (int h = 0; h < H; h++){ sesum[h] = 0.f; m[h] = -1e30f; }
  for (int t = lane; t < d; t += 64){
    int s = r0 + t;
    int sn = src_csr[s];
    if (t < CH) s_src[t] = sn;
    float al[H];
    if constexpr (H == 4){
      float4 av = *(const float4*)(al_src + (size_t)sn*4);
      float4 ev = *(const float4*)(edot + (size_t)s*4);
      al[0]=av.x+ad[0]+ev.x; al[1]=av.y+ad[1]+ev.y; al[2]=av.z+ad[2]+ev.z; al[3]=av.w+ad[3]+ev.w;
      sesum[0]+=ev.x; sesum[1]+=ev.y; sesum[2]+=ev.z; sesum[3]+=ev.w;
    } else {
      float ev = edot[s];
      al[0] = al_src[sn] + ad[0] + ev;
      sesum[0] += ev;
    }
    #pragma unroll
    for (int h = 0; h < H; h++){
      float a = al[h]; a = a > 0.f ? a : 0.2f*a;
      if (t < CH) s_e[t*H+h] = a;
      m[h] = fmaxf(m[h], a);
    }
  }
  float invd = (d > 0) ? 1.f/(float)d : 0.f;
  float sa[H];
  #pragma unroll
  for (int h = 0; h < H; h++){
    sesum[h] = wsum64(sesum[h]);
    m[h] = wmax64(m[h]);
    float a = asi[h] + ad[h] + sesum[h]*invd;
    sa[h] = a > 0.f ? a : 0.2f*a;
    m[h] = fmaxf(m[h], sa[h]);
  }
  // pass 2: exp + unnormalized bf16 gather, chunked (per-wave LDS, no block barrier)
  float acc[H], dpart[H];
  #pragma unroll
  for (int h = 0; h < H; h++){ acc[h] = 0.f; dpart[h] = 0.f; }
  int c0 = 0;
  while (c0 < d){
    int cl = min(CH, d - c0);
    if (c0 > 0){                       // degree > 128: reload (rare, Poisson(16))
      for (int t = lane; t < cl; t += 64){
        int s = r0 + c0 + t;
        int sn = src_csr[s];
        s_src[t] = sn;
        if constexpr (H == 4){
          float4 av = *(const float4*)(al_src + (size_t)sn*4);
          float4 ev = *(const float4*)(edot + (size_t)s*4);
          float a0=av.x+ad[0]+ev.x, a1=av.y+ad[1]+ev.y, a2=av.z+ad[2]+ev.z, a3=av.w+ad[3]+ev.w;
          s_e[t*4+0]=a0>0.f?a0:0.2f*a0; s_e[t*4+1]=a1>0.f?a1:0.2f*a1;
          s_e[t*4+2]=a2>0.f?a2:0.2f*a2; s_e[t*4+3]=a3>0.f?a3:0.2f*a3;
        } else {
          float a = al_src[sn] + ad[0] + edot[s];
          s_e[t] = a > 0.f ? a : 0.2f*a;
        }
      }
    }
    for (int t = lane; t < cl; t += 64){
      #pragma unroll
      for (int h = 0; h < H; h++){
        float e = __expf(s_e[t*H+h] - m[h]);
        s_e[t*H+h] = e;
        dpart[h] += e;
      }
    }
    __builtin_amdgcn_wave_barrier();   // wave-synchronous LDS: compiler orders via lgkmcnt
    if constexpr (H == 4){
      const int hd = lane >> 4;
      for (int t = 0; t < cl; t++){
        int sn = s_src[t];
        float w = s_e[t*4 + hd];
        ushort4 u = *(const ushort4*)(xsb + (size_t)sn*256 + 4*lane);   // 512B/row coalesced
        acc[0] += w*b2f(u.x); acc[1] += w*b2f(u.y); acc[2] += w*b2f(u.z); acc[3] += w*b2f(u.w);
      }
    } else {
      for (int t = 0; t < cl; t++){
        acc[0] += s_e[t] * b2f(xsb[(size_t)s_src[t]*64 + lane]);        // 128B/row coalesced
      }
    }
    c0 += CH;
  }
  // self loop
  float es[H];
  #pragma unroll
  for (int h = 0; h < H; h++) es[h] = __expf(sa[h] - m[h]);
  if (lane == 0){
    #pragma unroll
    for (int h = 0; h < H; h++) dpart[h] += es[h];
  }
  if constexpr (H == 4){
    const int hd = lane >> 4;
    ushort4 u = *(const ushort4*)(xsb + (size_t)i*256 + 4*lane);
    float w = es[hd];
    acc[0] += w*b2f(u.x); acc[1] += w*b2f(u.y); acc[2] += w*b2f(u.z); acc[3] += w*b2f(u.w);
  } else {
    acc[0] += es[0] * b2f(xsb[(size_t)i*64 + lane]);
  }
  float denom[H];
  #pragma unroll
  for (int h = 0; h < H; h++) denom[h] = wsum64(dpart[h]);
  if constexpr (H == 4){
    const int hd = lane >> 4;
    float inv = 1.f / denom[hd];
    float4 bv = *(const float4*)(bias + 4*lane);
    float4 o;
    o.x = acc[0]*inv + bv.x; o.y = acc[1]*inv + bv.y;
    o.z = acc[2]*inv + bv.z; o.w = acc[3]*inv + bv.w;
    *(float4*)(out + (size_t)i*256 + 4*lane) = o;
  } else {
    out[(size_t)i*64 + lane] = acc[0]/denom[0] + bias[lane];
  }
}

// ---------------- BN ----------------
template<int F>
__global__ __launch_bounds__(256) void bn_stats_kernel(const float* __restrict__ h,
    float* __restrict__ cs, float* __restrict__ csq){
  constexpr int RP = 256 / F;
  int col = threadIdx.x % F;
  int ro  = threadIdx.x / F;
  float s = 0.f, s2 = 0.f;
  for (int r = blockIdx.x*RP + ro; r < NN; r += 256*RP){
    float v = h[(size_t)r*F + col];
    s += v; s2 += v*v;
  }
  atomicAdd(&cs[col], s);
  atomicAdd(&csq[col], s2);
}

__global__ void bn_scale_kernel(const float* __restrict__ cs, const float* __restrict__ csq,
    const float* __restrict__ g, const float* __restrict__ b,
    float* __restrict__ scale, float* __restrict__ shift, int F){
  int f = threadIdx.x;
  if (f >= F) return;
  float mu  = cs[f]  * (1.f/NN);
  float var = csq[f] * (1.f/NN) - mu*mu;
  float rs  = rsqrtf(var + 1e-5f);
  float sc  = rs * g[f];
  scale[f] = sc;
  shift[f] = b[f] - mu*sc;
}

// ---------------- pooling ----------------
__global__ void gp_kernel(const int* __restrict__ batch, int* __restrict__ gp){
  int n = blockIdx.x*256 + threadIdx.x;
  if (n >= NN) return;
  int b = batch[n];
  if (n == 0){ for (int g = 0; g <= b; g++) gp[g] = 0; }
  else { int bp = batch[n-1]; for (int g = bp+1; g <= b; g++) gp[g] = n; }
  if (n == NN-1){ for (int g = b+1; g <= BB; g++) gp[g] = NN; }
}

__global__ __launch_bounds__(256) void gate_kernel(const float* __restrict__ h, const float* __restrict__ scale,
    const float* __restrict__ shift, const float* __restrict__ Wg, const float* __restrict__ bg,
    float* __restrict__ hn, float* __restrict__ gate){
  int wid = threadIdx.x >> 6, lane = threadIdx.x & 63;
  int n = blockIdx.x*4 + wid;
  float v = h[(size_t)n*64 + lane];
  float xx = fmaxf(fmaf(v, scale[lane], shift[lane]), 0.f);
  hn[(size_t)n*64 + lane] = xx;
  float p = wsum64(xx * Wg[lane]);
  if (lane == 0) gate[n] = p + bg[0];
}

__global__ __launch_bounds__(256) void pool_kernel(const int* __restrict__ gp, const float* __restrict__ gate,
    const float* __restrict__ hn, float* __restrict__ out){
  __shared__ float red[256];
  __shared__ float wred_[4];
  int b = blockIdx.x, tid = threadIdx.x;
  int s = gp[b], e = gp[b+1];
  if (e <= s){ if (tid < 64) out[b*64 + tid] = 0.f; return; }
  float mloc = -1e30f;
  for (int n = s + tid; n < e; n += 256) mloc = fmaxf(mloc, gate[n]);
  mloc = wmax64(mloc);
  if ((tid & 63) == 0) red[tid >> 6] = mloc;
  __syncthreads();
  float m = fmaxf(fmaxf(red[0], red[1]), fmaxf(red[2], red[3]));
  __syncthreads();
  int col = tid & 63, ro = tid >> 6;
  float acc = 0.f, wp = 0.f;
  for (int n = s + ro; n < e; n += 4){
    float w = __expf(gate[n] - m);
    if (col == 0) wp += w;
    acc += w * hn[(size_t)n*64 + col];
  }
  red[tid] = acc;
  if (col == 0) wred_[ro] = wp;
  __syncthreads();
  if (ro == 0){
    float tot = red[col] + red[64+col] + red[128+col] + red[192+col];
    float wsm = wred_[0] + wred_[1] + wred_[2] + wred_[3];
    out[b*64 + col] = tot / wsm;
  }
}

// ---------------- host ----------------
extern "C" void kernel_launch(void* const* d_in, const int* in_sizes, int n_in,
                              void* d_out, int out_size, void* d_ws, size_t ws_size,
                              hipStream_t stream){
  const float* x     = (const float*)d_in[0];
  const float* ea    = (const float*)d_in[1];
  const int*   ei    = (const int*)d_in[2];
  const int*   batch = (const int*)d_in[3];
  const float* W1    = (const float*)d_in[4];
  const float* We1   = (const float*)d_in[5];
  const float* as1   = (const float*)d_in[6];
  const float* ad1   = (const float*)d_in[7];
  const float* ae1   = (const float*)d_in[8];
  const float* bias1 = (const float*)d_in[9];
  const float* g1    = (const float*)d_in[10];
  const float* b1    = (const float*)d_in[11];
  const float* W2    = (const float*)d_in[12];
  const float* We2   = (const float*)d_in[13];
  const float* as2   = (const float*)d_in[14];
  const float* ad2   = (const float*)d_in[15];
  const float* ae2   = (const float*)d_in[16];
  const float* bias2 = (const float*)d_in[17];
  const float* g2    = (const float*)d_in[18];
  const float* b2    = (const float*)d_in[19];
  const float* Wg    = (const float*)d_in[20];
  const float* bg    = (const float*)d_in[21];
  const int* srcI = ei;
  const int* dstI = ei + EE;

  char* ws = (char*)d_ws;
  int*   deg    = (int*)(ws + 0);
  int*   cursor = (int*)(ws + 120064);
  float* stats  = (float*)(ws + 240128);    // cs1@0 csq1@256 cs2@512 csq2@576
  int*   rowptr = (int*)(ws + 244224);
  int*   slot_e = (int*)(ws + 364544);
  int*   srccsr = (int*)(ws + 2284544);
  float* wae    = (float*)(ws + 4204544);   // 160 floats
  float* ss     = (float*)(ws + 4205312);   // scale1@0 shift1@256 scale2@512 shift2@576
  float* alsrc  = (float*)(ws + 4209408);
  float* aldst  = (float*)(ws + 4689408);
  int*   gp     = (int*)(ws + 5169408);
  float* gateb  = (float*)(ws + 5169920);
  float* edot1  = (float*)(ws + 5289920);   // E*4 floats
  float* edot2  = (float*)(ws + 12969920);  // E floats
  unsigned short* xs1b = (unsigned short*)(ws + 14889920);  // 30000*256 bf16 (dead after agg4)
  float* h2     = (float*)(ws + 14889920);  // reuse: 30000*64 fp32 (written by agg1)
  float* hn     = (float*)(ws + 22569920);  // reuse upper half of xs1b region
  float* h1     = (float*)(ws + 30249920);  // 30000*256 fp32
  unsigned short* xs2b = (unsigned short*)(ws + 60969920);  // 30000*64 bf16
  // total ~64.8 MB

  (void)hipMemsetAsync(ws, 0, 244224, stream);   // deg, cursor, stats

  hist_kernel<<<1875, 256, 0, stream>>>(dstI, deg);
  scan_kernel<<<1, 1024, 0, stream>>>(deg, rowptr);
  scatter_kernel<<<1875, 256, 0, stream>>>(srcI, dstI, rowptr, cursor, slot_e, srccsr);
  wae_kernel<<<1, 192, 0, stream>>>(We1, ae1, We2, ae2, wae);
  edot_kernel<<<1875, 256, 0, stream>>>(ea, wae, slot_e, edot1, edot2);

  // ---- layer 1 (H=4, F=256) ----
  gemm_kernel<128, 256, false, 4><<<dim3(469, 4), 256, 0, stream>>>(
      x, W1, nullptr, nullptr, as1, ad1, xs1b, alsrc, aldst);
  agg_kernel<4><<<7500, 256, 0, stream>>>(rowptr, srccsr, edot1, alsrc, aldst, xs1b, bias1, h1);
  bn_stats_kernel<256><<<256, 256, 0, stream>>>(h1, stats + 0, stats + 256);
  bn_scale_kernel<<<1, 256, 0, stream>>>(stats + 0, stats + 256, g1, b1, ss + 0, ss + 256, 256);

  // ---- layer 2 (H=1, F=64), BN+ReLU fused into GEMM A-load ----
  gemm_kernel<256, 64, true, 1><<<dim3(469, 1), 256, 0, stream>>>(
      h1, W2, ss + 0, ss + 256, as2, ad2, xs2b, alsrc, aldst);
  agg_kernel<1><<<7500, 256, 0, stream>>>(rowptr, srccsr, edot2, alsrc, aldst, xs2b, bias2, h2);
  bn_stats_kernel<64><<<256, 256, 0, stream>>>(h2, stats + 512, stats + 576);
  bn_scale_kernel<<<1, 256, 0, stream>>>(stats + 512, stats + 576, g2, b2, ss + 512, ss + 576, 64);

  // ---- pool ----
  gp_kernel<<<118, 256, 0, stream>>>(batch, gp);
  gate_kernel<<<7500, 256, 0, stream>>>(h2, ss + 512, ss + 576, Wg, bg, hn, gateb);
  pool_kernel<<<64, 256, 0, stream>>>(gp, gateb, hn, (float*)d_out);
}

// Round 3
// 502.376 us; speedup vs baseline: 1.0929x; 1.0089x over previous
//
#include <hip/hip_runtime.h>
#include <math.h>

#define NN 30000
#define EE 480000
#define BB 64

typedef __bf16 b16x8 __attribute__((ext_vector_type(8)));
typedef float  f32x4 __attribute__((ext_vector_type(4)));

// ---------------- helpers ----------------
__device__ __forceinline__ float wsum64(float v){
  #pragma unroll
  for (int m = 32; m >= 1; m >>= 1) v += __shfl_xor(v, m, 64);
  return v;
}
__device__ __forceinline__ float wmax64(float v){
  #pragma unroll
  for (int m = 32; m >= 1; m >>= 1) v = fmaxf(v, __shfl_xor(v, m, 64));
  return v;
}
__device__ __forceinline__ float wsum16(float v){
  #pragma unroll
  for (int m = 1; m < 16; m <<= 1) v += __shfl_xor(v, m, 64);
  return v;
}
__device__ __forceinline__ unsigned short f2b(float f){   // fp32 -> bf16 RNE
  union { float f; unsigned u; } v; v.f = f;
  unsigned r = v.u + 0x7fffu + ((v.u >> 16) & 1u);
  return (unsigned short)(r >> 16);
}
__device__ __forceinline__ float b2f(unsigned short u){
  union { unsigned u; float f; } v; v.u = ((unsigned)u) << 16;
  return v.f;
}

// ---------------- CSR build ----------------
__global__ void hist_kernel(const int* __restrict__ dst, int* __restrict__ deg){
  int e = blockIdx.x*256 + threadIdx.x;
  if (e < EE) atomicAdd(&deg[dst[e]], 1);
}

__global__ __launch_bounds__(1024) void scan_kernel(const int* __restrict__ deg, int* __restrict__ rowptr){
  __shared__ int s[1024];
  int tid = threadIdx.x;
  const int PER = 30;
  int base = tid * PER;
  int sum = 0;
  for (int j = 0; j < PER; j++){ int idx = base+j; if (idx < NN) sum += deg[idx]; }
  s[tid] = sum; __syncthreads();
  for (int off = 1; off < 1024; off <<= 1){
    int v = 0;
    if (tid >= off) v = s[tid-off];
    __syncthreads();
    s[tid] += v;
    __syncthreads();
  }
  int run = s[tid] - sum;
  for (int j = 0; j < PER; j++){
    int idx = base+j;
    if (idx < NN){ rowptr[idx] = run; run += deg[idx]; }
  }
  if (tid == 1023) rowptr[NN] = s[1023];
}

__global__ void scatter_kernel(const int* __restrict__ src, const int* __restrict__ dst,
    const int* __restrict__ rowptr, int* __restrict__ cursor,
    int* __restrict__ slot_e, int* __restrict__ srccsr){
  int e = blockIdx.x*256 + threadIdx.x;
  if (e >= EE) return;
  int d = dst[e];
  int slot = rowptr[d] + atomicAdd(&cursor[d], 1);
  slot_e[e] = slot;
  srccsr[slot] = src[e];
}

// ---------------- bf16 prep: x -> xb, W1^T -> W1t (bf16), W2^T -> W2t (bf16) ----------------
__global__ __launch_bounds__(256) void cvt_x_kernel(const float* __restrict__ x, unsigned short* __restrict__ xb){
  int t = blockIdx.x*256 + threadIdx.x;     // 480000 threads, 8 elems each
  size_t base = (size_t)t*8;
  float4 v0 = *(const float4*)(x + base);
  float4 v1 = *(const float4*)(x + base + 4);
  unsigned short o[8];
  o[0]=f2b(v0.x); o[1]=f2b(v0.y); o[2]=f2b(v0.z); o[3]=f2b(v0.w);
  o[4]=f2b(v1.x); o[5]=f2b(v1.y); o[6]=f2b(v1.z); o[7]=f2b(v1.w);
  ushort4* dst = (ushort4*)(xb + base);
  dst[0] = make_ushort4(o[0],o[1],o[2],o[3]);
  dst[1] = make_ushort4(o[4],o[5],o[6],o[7]);
}

__global__ void wt_kernel(const float* __restrict__ W1, const float* __restrict__ W2,
                          unsigned short* __restrict__ W1t, unsigned short* __restrict__ W2t){
  int n = threadIdx.x;
  for (int k = 0; k < 128; k++) W1t[n*128 + k] = f2b(W1[k*256 + n]);
  if (n < 64){
    for (int k = 0; k < 256; k++) W2t[n*256 + k] = f2b(W2[k*64 + n]);
  }
}

// ---------------- wae precompute for BOTH layers ----------------
__global__ void wae_kernel(const float* __restrict__ We1, const float* __restrict__ ae1,
                           const float* __restrict__ We2, const float* __restrict__ ae2,
                           float* __restrict__ wae){
  int t = threadIdx.x;
  if (t < 128){
    int h = t >> 5, k = t & 31;
    float s = 0.f;
    for (int f = 0; f < 64; f++) s += We1[k*256 + h*64 + f] * ae1[h*64 + f];
    wae[h*32 + k] = s;
  } else if (t < 160){
    int k = t - 128;
    float s = 0.f;
    for (int f = 0; f < 64; f++) s += We2[k*64 + f] * ae2[f];
    wae[128 + k] = s;
  }
}

// one pass over ea: 5 dots per edge (4 layer-1 heads + 1 layer-2), written in CSR slot order
__global__ __launch_bounds__(256) void edot_kernel(const float* __restrict__ ea, const float* __restrict__ wae,
    const int* __restrict__ slot_e, float* __restrict__ edot1, float* __restrict__ edot2){
  __shared__ float s_w[160];
  if (threadIdx.x < 160) s_w[threadIdx.x] = wae[threadIdx.x];
  __syncthreads();
  int e = blockIdx.x*256 + threadIdx.x;
  if (e >= EE) return;
  const float4* row = (const float4*)(ea + (size_t)e*32);
  float4 r[8];
  #pragma unroll
  for (int q = 0; q < 8; q++) r[q] = row[q];
  const float4* wv = (const float4*)s_w;
  float dots[5];
  #pragma unroll
  for (int h = 0; h < 5; h++){
    float s = 0.f;
    #pragma unroll
    for (int q = 0; q < 8; q++){
      float4 w = wv[h*8 + q];
      s += r[q].x*w.x + r[q].y*w.y + r[q].z*w.z + r[q].w*w.w;
    }
    dots[h] = s;
  }
  int slot = slot_e[e];
  float4 o; o.x = dots[0]; o.y = dots[1]; o.z = dots[2]; o.w = dots[3];
  *(float4*)(edot1 + (size_t)slot*4) = o;
  edot2[slot] = dots[4];
}

// ---------------- MFMA bf16 GEMM, 128x64 tile, fused BN/ReLU(A) + al epilogue + bf16 out ----------------
// A: row-major [NN x KTOT] (bf16 if !NORM, fp32+scale/shift if NORM). Bt: n-major [HGRID*64 x KTOT] bf16.
// blockIdx.y = head. out: bf16 [NN x HGRID*64]. alsrc/aldst: [NN x HGRID].
template<int KTOT, bool NORM, int HGRID>
__global__ __launch_bounds__(256) void gemm_mfma(const unsigned short* __restrict__ Abf,
    const float* __restrict__ Af, const unsigned short* __restrict__ Bt,
    const float* __restrict__ scale, const float* __restrict__ shift,
    const float* __restrict__ a_s, const float* __restrict__ a_d,
    unsigned short* __restrict__ out, float* __restrict__ alsrc, float* __restrict__ aldst){
  __shared__ unsigned short As[128*136];   // 128 rows x (128+8) bf16
  __shared__ unsigned short Bs[64*136];
  const int tid = threadIdx.x;
  const int w = tid >> 6, lane = tid & 63;
  const int c = lane & 15, g = lane >> 4;
  const int m0 = blockIdx.x * 128;
  const int head = blockIdx.y;
  const int NCOLT = HGRID * 64;
  f32x4 acc[2][4];
  #pragma unroll
  for (int mt = 0; mt < 2; mt++)
    #pragma unroll
    for (int nt = 0; nt < 4; nt++) acc[mt][nt] = (f32x4){0.f,0.f,0.f,0.f};

  for (int kp = 0; kp < KTOT; kp += 128){
    // stage A panel: 128 rows x 128 k
    if constexpr (!NORM){
      #pragma unroll
      for (int q = 0; q < 8; q++){
        int ch = tid*8 + q;                 // 2048 chunks of 8 bf16
        int r = ch >> 4, off = (ch & 15)*8;
        int grow = m0 + r;
        if (grow < NN){
          *(ulonglong2*)&As[r*136 + off] = *(const ulonglong2*)(Abf + (size_t)grow*KTOT + kp + off);
        } else {
          *(ulonglong2*)&As[r*136 + off] = (ulonglong2){0ull, 0ull};
        }
      }
    } else {
      #pragma unroll
      for (int q = 0; q < 16; q++){
        int ch = tid*16 + q;                // 4096 chunks of 4 fp32
        int r = ch >> 5, off = (ch & 31)*4;
        int grow = m0 + r;
        ushort4 o;
        if (grow < NN){
          float4 v = *(const float4*)(Af + (size_t)grow*KTOT + kp + off);
          float4 sc = *(const float4*)(scale + kp + off);
          float4 sh = *(const float4*)(shift + kp + off);
          o.x = f2b(fmaxf(fmaf(v.x, sc.x, sh.x), 0.f));
          o.y = f2b(fmaxf(fmaf(v.y, sc.y, sh.y), 0.f));
          o.z = f2b(fmaxf(fmaf(v.z, sc.z, sh.z), 0.f));
          o.w = f2b(fmaxf(fmaf(v.w, sc.w, sh.w), 0.f));
        } else o = make_ushort4(0,0,0,0);
        *(ushort4*)&As[r*136 + off] = o;
      }
    }
    // stage B panel: 64 n-rows x 128 k (Bt is n-major)
    #pragma unroll
    for (int q = 0; q < 4; q++){
      int ch = tid*4 + q;                   // 1024 chunks of 8 bf16
      int n = ch >> 4, off = (ch & 15)*8;
      *(ulonglong2*)&Bs[n*136 + off] = *(const ulonglong2*)(Bt + (size_t)(head*64 + n)*KTOT + kp + off);
    }
    __syncthreads();
    #pragma unroll
    for (int k0 = 0; k0 < 128; k0 += 32){
      b16x8 afr[2], bfr[4];
      #pragma unroll
      for (int mt = 0; mt < 2; mt++)
        afr[mt] = *(const b16x8*)&As[(w*32 + mt*16 + c)*136 + k0 + g*8];
      #pragma unroll
      for (int nt = 0; nt < 4; nt++)
        bfr[nt] = *(const b16x8*)&Bs[(nt*16 + c)*136 + k0 + g*8];
      #pragma unroll
      for (int mt = 0; mt < 2; mt++)
        #pragma unroll
        for (int nt = 0; nt < 4; nt++)
          acc[mt][nt] = __builtin_amdgcn_mfma_f32_16x16x32_bf16(afr[mt], bfr[nt], acc[mt][nt], 0, 0, 0);
    }
    __syncthreads();
  }
  // epilogue: al logits via 16-lane shuffle + bf16 store
  float asv[4], adv[4];
  #pragma unroll
  for (int nt = 0; nt < 4; nt++){
    asv[nt] = a_s[head*64 + nt*16 + c];
    adv[nt] = a_d[head*64 + nt*16 + c];
  }
  #pragma unroll
  for (int mt = 0; mt < 2; mt++){
    int base_row = m0 + w*32 + mt*16 + g*4;
    #pragma unroll
    for (int r = 0; r < 4; r++){
      int row = base_row + r;
      float ps = 0.f, pd = 0.f;
      #pragma unroll
      for (int nt = 0; nt < 4; nt++){
        ps += acc[mt][nt][r] * asv[nt];
        pd += acc[mt][nt][r] * adv[nt];
      }
      ps = wsum16(ps); pd = wsum16(pd);
      if (row < NN){
        if (c == 0){
          alsrc[(size_t)row*HGRID + head] = ps;
          aldst[(size_t)row*HGRID + head] = pd;
        }
        #pragma unroll
        for (int nt = 0; nt < 4; nt++)
          out[(size_t)row*NCOLT + head*64 + nt*16 + c] = f2b(acc[mt][nt][r]);
      }
    }
  }
}

// ---------------- segment softmax + bf16 weighted gather: one wave per node, 4 nodes/block ----------------
template<int H>
__global__ __launch_bounds__(256) void agg_kernel(const int* __restrict__ rowptr,
    const int* __restrict__ src_csr, const float* __restrict__ edot,
    const float* __restrict__ al_src, const float* __restrict__ al_dst,
    const unsigned short* __restrict__ xsb, const float* __restrict__ bias,
    float* __restrict__ out){
  constexpr int CH = 128;
  __shared__ float s_e_all[4][CH*H];
  __shared__ int   s_src_all[4][CH];
  const int wid  = threadIdx.x >> 6;
  const int lane = threadIdx.x & 63;
  const int i = blockIdx.x*4 + wid;
  float* s_e  = s_e_all[wid];
  int*   s_src = s_src_all[wid];
  const int r0 = rowptr[i];
  const int d  = rowptr[i+1] - r0;
  float ad[H], asi[H];
  #pragma unroll
  for (int h = 0; h < H; h++){ ad[h] = al_dst[(size_t)i*H+h]; asi[h] = al_src[(size_t)i*H+h]; }
  float sesum[H], m[H];
  #pragma unroll
  for (int h = 0; h < H; h++){ sesum[h] = 0.f; m[h] = -1e30f; }
  for (int t = lane; t < d; t += 64){
    int s = r0 + t;
    int sn = src_csr[s];
    if (t < CH) s_src[t] = sn;
    float al[H];
    if constexpr (H == 4){
      float4 av = *(const float4*)(al_src + (size_t)sn*4);
      float4 ev = *(const float4*)(edot + (size_t)s*4);
      al[0]=av.x+ad[0]+ev.x; al[1]=av.y+ad[1]+ev.y; al[2]=av.z+ad[2]+ev.z; al[3]=av.w+ad[3]+ev.w;
      sesum[0]+=ev.x; sesum[1]+=ev.y; sesum[2]+=ev.z; sesum[3]+=ev.w;
    } else {
      float ev = edot[s];
      al[0] = al_src[sn] + ad[0] + ev;
      sesum[0] += ev;
    }
    #pragma unroll
    for (int h = 0; h < H; h++){
      float a = al[h]; a = a > 0.f ? a : 0.2f*a;
      if (t < CH) s_e[t*H+h] = a;
      m[h] = fmaxf(m[h], a);
    }
  }
  float invd = (d > 0) ? 1.f/(float)d : 0.f;
  float sa[H];
  #pragma unroll
  for (int h = 0; h < H; h++){
    sesum[h] = wsum64(sesum[h]);
    m[h] = wmax64(m[h]);
    float a = asi[h] + ad[h] + sesum[h]*invd;
    sa[h] = a > 0.f ? a : 0.2f*a;
    m[h] = fmaxf(m[h], sa[h]);
  }
  float acc[H], dpart[H];
  #pragma unroll
  for (int h = 0; h < H; h++){ acc[h] = 0.f; dpart[h] = 0.f; }
  int c0 = 0;
  while (c0 < d){
    int cl = min(CH, d - c0);
    if (c0 > 0){
      for (int t = lane; t < cl; t += 64){
        int s = r0 + c0 + t;
        int sn = src_csr[s];
        s_src[t] = sn;
        if constexpr (H == 4){
          float4 av = *(const float4*)(al_src + (size_t)sn*4);
          float4 ev = *(const float4*)(edot + (size_t)s*4);
          float a0=av.x+ad[0]+ev.x, a1=av.y+ad[1]+ev.y, a2=av.z+ad[2]+ev.z, a3=av.w+ad[3]+ev.w;
          s_e[t*4+0]=a0>0.f?a0:0.2f*a0; s_e[t*4+1]=a1>0.f?a1:0.2f*a1;
          s_e[t*4+2]=a2>0.f?a2:0.2f*a2; s_e[t*4+3]=a3>0.f?a3:0.2f*a3;
        } else {
          float a = al_src[sn] + ad[0] + edot[s];
          s_e[t] = a > 0.f ? a : 0.2f*a;
        }
      }
    }
    for (int t = lane; t < cl; t += 64){
      #pragma unroll
      for (int h = 0; h < H; h++){
        float e = __expf(s_e[t*H+h] - m[h]);
        s_e[t*H+h] = e;
        dpart[h] += e;
      }
    }
    __builtin_amdgcn_wave_barrier();
    if constexpr (H == 4){
      const int hd = lane >> 4;
      for (int t = 0; t < cl; t++){
        int sn = s_src[t];
        float w = s_e[t*4 + hd];
        ushort4 u = *(const ushort4*)(xsb + (size_t)sn*256 + 4*lane);
        acc[0] += w*b2f(u.x); acc[1] += w*b2f(u.y); acc[2] += w*b2f(u.z); acc[3] += w*b2f(u.w);
      }
    } else {
      for (int t = 0; t < cl; t++){
        acc[0] += s_e[t] * b2f(xsb[(size_t)s_src[t]*64 + lane]);
      }
    }
    c0 += CH;
  }
  float es[H];
  #pragma unroll
  for (int h = 0; h < H; h++) es[h] = __expf(sa[h] - m[h]);
  if (lane == 0){
    #pragma unroll
    for (int h = 0; h < H; h++) dpart[h] += es[h];
  }
  if constexpr (H == 4){
    const int hd = lane >> 4;
    ushort4 u = *(const ushort4*)(xsb + (size_t)i*256 + 4*lane);
    float w = es[hd];
    acc[0] += w*b2f(u.x); acc[1] += w*b2f(u.y); acc[2] += w*b2f(u.z); acc[3] += w*b2f(u.w);
  } else {
    acc[0] += es[0] * b2f(xsb[(size_t)i*64 + lane]);
  }
  float denom[H];
  #pragma unroll
  for (int h = 0; h < H; h++) denom[h] = wsum64(dpart[h]);
  if constexpr (H == 4){
    const int hd = lane >> 4;
    float inv = 1.f / denom[hd];
    float4 bv = *(const float4*)(bias + 4*lane);
    float4 o;
    o.x = acc[0]*inv + bv.x; o.y = acc[1]*inv + bv.y;
    o.z = acc[2]*inv + bv.z; o.w = acc[3]*inv + bv.w;
    *(float4*)(out + (size_t)i*256 + 4*lane) = o;
  } else {
    out[(size_t)i*64 + lane] = acc[0]/denom[0] + bias[lane];
  }
}

// ---------------- BN ----------------
template<int F>
__global__ __launch_bounds__(256) void bn_stats_kernel(const float* __restrict__ h,
    float* __restrict__ cs, float* __restrict__ csq){
  constexpr int RP = 256 / F;
  int col = threadIdx.x % F;
  int ro  = threadIdx.x / F;
  float s = 0.f, s2 = 0.f;
  for (int r = blockIdx.x*RP + ro; r < NN; r += 256*RP){
    float v = h[(size_t)r*F + col];
    s += v; s2 += v*v;
  }
  atomicAdd(&cs[col], s);
  atomicAdd(&csq[col], s2);
}

__global__ void bn_scale_kernel(const float* __restrict__ cs, const float* __restrict__ csq,
    const float* __restrict__ g, const float* __restrict__ b,
    float* __restrict__ scale, float* __restrict__ shift, int F){
  int f = threadIdx.x;
  if (f >= F) return;
  float mu  = cs[f]  * (1.f/NN);
  float var = csq[f] * (1.f/NN) - mu*mu;
  float rs  = rsqrtf(var + 1e-5f);
  float sc  = rs * g[f];
  scale[f] = sc;
  shift[f] = b[f] - mu*sc;
}

// ---------------- pooling ----------------
__global__ void gp_kernel(const int* __restrict__ batch, int* __restrict__ gp){
  int n = blockIdx.x*256 + threadIdx.x;
  if (n >= NN) return;
  int b = batch[n];
  if (n == 0){ for (int g = 0; g <= b; g++) gp[g] = 0; }
  else { int bp = batch[n-1]; for (int g = bp+1; g <= b; g++) gp[g] = n; }
  if (n == NN-1){ for (int g = b+1; g <= BB; g++) gp[g] = NN; }
}

__global__ __launch_bounds__(256) void gate_kernel(const float* __restrict__ h, const float* __restrict__ scale,
    const float* __restrict__ shift, const float* __restrict__ Wg, const float* __restrict__ bg,
    float* __restrict__ hn, float* __restrict__ gate){
  int wid = threadIdx.x >> 6, lane = threadIdx.x & 63;
  int n = blockIdx.x*4 + wid;
  float v = h[(size_t)n*64 + lane];
  float xx = fmaxf(fmaf(v, scale[lane], shift[lane]), 0.f);
  hn[(size_t)n*64 + lane] = xx;
  float p = wsum64(xx * Wg[lane]);
  if (lane == 0) gate[n] = p + bg[0];
}

__global__ __launch_bounds__(256) void pool_kernel(const int* __restrict__ gp, const float* __restrict__ gate,
    const float* __restrict__ hn, float* __restrict__ out){
  __shared__ float red[256];
  __shared__ float wred_[4];
  int b = blockIdx.x, tid = threadIdx.x;
  int s = gp[b], e = gp[b+1];
  if (e <= s){ if (tid < 64) out[b*64 + tid] = 0.f; return; }
  float mloc = -1e30f;
  for (int n = s + tid; n < e; n += 256) mloc = fmaxf(mloc, gate[n]);
  mloc = wmax64(mloc);
  if ((tid & 63) == 0) red[tid >> 6] = mloc;
  __syncthreads();
  float m = fmaxf(fmaxf(red[0], red[1]), fmaxf(red[2], red[3]));
  __syncthreads();
  int col = tid & 63, ro = tid >> 6;
  float acc = 0.f, wp = 0.f;
  for (int n = s + ro; n < e; n += 4){
    float w = __expf(gate[n] - m);
    if (col == 0) wp += w;
    acc += w * hn[(size_t)n*64 + col];
  }
  red[tid] = acc;
  if (col == 0) wred_[ro] = wp;
  __syncthreads();
  if (ro == 0){
    float tot = red[col] + red[64+col] + red[128+col] + red[192+col];
    float wsm = wred_[0] + wred_[1] + wred_[2] + wred_[3];
    out[b*64 + col] = tot / wsm;
  }
}

// ---------------- host ----------------
extern "C" void kernel_launch(void* const* d_in, const int* in_sizes, int n_in,
                              void* d_out, int out_size, void* d_ws, size_t ws_size,
                              hipStream_t stream){
  const float* x     = (const float*)d_in[0];
  const float* ea    = (const float*)d_in[1];
  const int*   ei    = (const int*)d_in[2];
  const int*   batch = (const int*)d_in[3];
  const float* W1    = (const float*)d_in[4];
  const float* We1   = (const float*)d_in[5];
  const float* as1   = (const float*)d_in[6];
  const float* ad1   = (const float*)d_in[7];
  const float* ae1   = (const float*)d_in[8];
  const float* bias1 = (const float*)d_in[9];
  const float* g1    = (const float*)d_in[10];
  const float* b1    = (const float*)d_in[11];
  const float* W2    = (const float*)d_in[12];
  const float* We2   = (const float*)d_in[13];
  const float* as2   = (const float*)d_in[14];
  const float* ad2   = (const float*)d_in[15];
  const float* ae2   = (const float*)d_in[16];
  const float* bias2 = (const float*)d_in[17];
  const float* g2    = (const float*)d_in[18];
  const float* b2    = (const float*)d_in[19];
  const float* Wg    = (const float*)d_in[20];
  const float* bg    = (const float*)d_in[21];
  const int* srcI = ei;
  const int* dstI = ei + EE;

  char* ws = (char*)d_ws;
  int*   deg    = (int*)(ws + 0);
  int*   cursor = (int*)(ws + 120064);
  float* stats  = (float*)(ws + 240128);    // cs1@0 csq1@256 cs2@512 csq2@576
  int*   rowptr = (int*)(ws + 244224);
  int*   slot_e = (int*)(ws + 364544);
  int*   srccsr = (int*)(ws + 2284544);
  float* wae    = (float*)(ws + 4204544);   // 160 floats
  float* ss     = (float*)(ws + 4205312);   // scale1@0 shift1@256 scale2@512 shift2@576
  float* alsrc  = (float*)(ws + 4209408);
  float* aldst  = (float*)(ws + 4689408);
  int*   gp     = (int*)(ws + 5169408);
  float* gateb  = (float*)(ws + 5169920);
  float* edot1  = (float*)(ws + 5289920);   // E*4 floats
  float* edot2  = (float*)(ws + 12969920);  // E floats
  unsigned short* xs1b = (unsigned short*)(ws + 14889920);  // 30000*256 bf16 (dead after agg4)
  float* h2     = (float*)(ws + 14889920);  // reuse: 30000*64 fp32 (written by agg1)
  float* hn     = (float*)(ws + 22569920);
  float* h1     = (float*)(ws + 30249920);  // 30000*256 fp32
  unsigned short* xs2b = (unsigned short*)(ws + 60969920);  // 30000*64 bf16
  unsigned short* xb   = (unsigned short*)(ws + 64809920);  // 30000*128 bf16
  unsigned short* W1t  = (unsigned short*)(ws + 72489920);  // 256*128 bf16
  unsigned short* W2t  = (unsigned short*)(ws + 72555456);  // 64*256 bf16
  // total ~72.6 MB

  (void)hipMemsetAsync(ws, 0, 244224, stream);   // deg, cursor, stats

  hist_kernel<<<1875, 256, 0, stream>>>(dstI, deg);
  scan_kernel<<<1, 1024, 0, stream>>>(deg, rowptr);
  scatter_kernel<<<1875, 256, 0, stream>>>(srcI, dstI, rowptr, cursor, slot_e, srccsr);
  cvt_x_kernel<<<1875, 256, 0, stream>>>(x, xb);
  wt_kernel<<<1, 256, 0, stream>>>(W1, W2, W1t, W2t);
  wae_kernel<<<1, 192, 0, stream>>>(We1, ae1, We2, ae2, wae);
  edot_kernel<<<1875, 256, 0, stream>>>(ea, wae, slot_e, edot1, edot2);

  // ---- layer 1 (H=4): MFMA GEMM [30000x128]@[128x256] ----
  gemm_mfma<128, false, 4><<<dim3(235, 4), 256, 0, stream>>>(
      xb, nullptr, W1t, nullptr, nullptr, as1, ad1, xs1b, alsrc, aldst);
  agg_kernel<4><<<7500, 256, 0, stream>>>(rowptr, srccsr, edot1, alsrc, aldst, xs1b, bias1, h1);
  bn_stats_kernel<256><<<256, 256, 0, stream>>>(h1, stats + 0, stats + 256);
  bn_scale_kernel<<<1, 256, 0, stream>>>(stats + 0, stats + 256, g1, b1, ss + 0, ss + 256, 256);

  // ---- layer 2 (H=1): BN+ReLU fused into MFMA GEMM A-staging ----
  gemm_mfma<256, true, 1><<<dim3(235, 1), 256, 0, stream>>>(
      nullptr, h1, W2t, ss + 0, ss + 256, as2, ad2, xs2b, alsrc, aldst);
  agg_kernel<1><<<7500, 256, 0, stream>>>(rowptr, srccsr, edot2, alsrc, aldst, xs2b, bias2, h2);
  bn_stats_kernel<64><<<256, 256, 0, stream>>>(h2, stats + 512, stats + 576);
  bn_scale_kernel<<<1, 256, 0, stream>>>(stats + 512, stats + 576, g2, b2, ss + 512, ss + 576, 64);

  // ---- pool ----
  gp_kernel<<<118, 256, 0, stream>>>(batch, gp);
  gate_kernel<<<7500, 256, 0, stream>>>(h2, ss + 512, ss + 576, Wg, bg, hn, gateb);
  pool_kernel<<<64, 256, 0, stream>>>(gp, gateb, hn, (float*)d_out);
}

// Round 4
// 483.837 us; speedup vs baseline: 1.1347x; 1.0383x over previous
//
#include <hip/hip_runtime.h>
#include <math.h>

#define NN 30000
#define EE 480000
#define BB 64

typedef __bf16 b16x8 __attribute__((ext_vector_type(8)));
typedef float  f32x4 __attribute__((ext_vector_type(4)));

// ---------------- helpers ----------------
__device__ __forceinline__ float wsum64(float v){
  #pragma unroll
  for (int m = 32; m >= 1; m >>= 1) v += __shfl_xor(v, m, 64);
  return v;
}
__device__ __forceinline__ float wmax64(float v){
  #pragma unroll
  for (int m = 32; m >= 1; m >>= 1) v = fmaxf(v, __shfl_xor(v, m, 64));
  return v;
}
__device__ __forceinline__ float wsum16(float v){
  #pragma unroll
  for (int m = 1; m < 16; m <<= 1) v += __shfl_xor(v, m, 64);
  return v;
}
__device__ __forceinline__ unsigned short f2b(float f){   // fp32 -> bf16 RNE
  union { float f; unsigned u; } v; v.f = f;
  unsigned r = v.u + 0x7fffu + ((v.u >> 16) & 1u);
  return (unsigned short)(r >> 16);
}
__device__ __forceinline__ float b2f(unsigned short u){
  union { unsigned u; float f; } v; v.u = ((unsigned)u) << 16;
  return v.f;
}

// ---------------- CSR build ----------------
__global__ void hist_kernel(const int* __restrict__ dst, int* __restrict__ deg){
  int e = blockIdx.x*256 + threadIdx.x;
  if (e < EE) atomicAdd(&deg[dst[e]], 1);
}

__global__ __launch_bounds__(1024) void scan_kernel(const int* __restrict__ deg, int* __restrict__ rowptr){
  __shared__ int s[1024];
  int tid = threadIdx.x;
  const int PER = 30;
  int base = tid * PER;
  int sum = 0;
  for (int j = 0; j < PER; j++){ int idx = base+j; if (idx < NN) sum += deg[idx]; }
  s[tid] = sum; __syncthreads();
  for (int off = 1; off < 1024; off <<= 1){
    int v = 0;
    if (tid >= off) v = s[tid-off];
    __syncthreads();
    s[tid] += v;
    __syncthreads();
  }
  int run = s[tid] - sum;
  for (int j = 0; j < PER; j++){
    int idx = base+j;
    if (idx < NN){ rowptr[idx] = run; run += deg[idx]; }
  }
  if (tid == 1023) rowptr[NN] = s[1023];
}

// ---------------- prep: W transposes (bf16) + wae dots, one launch ----------------
// block 0: W1t/W2t. block 1: wae[0..127] layer1, wae[128..159] layer2.
__global__ void prep_kernel(const float* __restrict__ W1, const float* __restrict__ W2,
                            const float* __restrict__ We1, const float* __restrict__ ae1,
                            const float* __restrict__ We2, const float* __restrict__ ae2,
                            unsigned short* __restrict__ W1t, unsigned short* __restrict__ W2t,
                            float* __restrict__ wae){
  int t = threadIdx.x;
  if (blockIdx.x == 0){
    for (int k = 0; k < 128; k++) W1t[t*128 + k] = f2b(W1[k*256 + t]);
    if (t < 64){
      for (int k = 0; k < 256; k++) W2t[t*256 + k] = f2b(W2[k*64 + t]);
    }
  } else {
    if (t < 128){
      int h = t >> 5, k = t & 31;
      float s = 0.f;
      for (int f = 0; f < 64; f++) s += We1[k*256 + h*64 + f] * ae1[h*64 + f];
      wae[h*32 + k] = s;
    } else if (t < 160){
      int k = t - 128;
      float s = 0.f;
      for (int f = 0; f < 64; f++) s += We2[k*64 + f] * ae2[f];
      wae[128 + k] = s;
    }
  }
}

// ---------------- fused edge pass: CSR scatter + 5 edge dots, written in slot order ----------------
__global__ __launch_bounds__(256) void edot_scatter_kernel(const float* __restrict__ ea,
    const float* __restrict__ wae, const int* __restrict__ src, const int* __restrict__ dst,
    const int* __restrict__ rowptr, int* __restrict__ cursor,
    int* __restrict__ srccsr, float* __restrict__ edot1, float* __restrict__ edot2){
  __shared__ float s_w[160];
  if (threadIdx.x < 160) s_w[threadIdx.x] = wae[threadIdx.x];
  __syncthreads();
  int e = blockIdx.x*256 + threadIdx.x;
  if (e >= EE) return;
  const float4* row = (const float4*)(ea + (size_t)e*32);
  float4 r[8];
  #pragma unroll
  for (int q = 0; q < 8; q++) r[q] = row[q];
  const float4* wv = (const float4*)s_w;
  float dots[5];
  #pragma unroll
  for (int h = 0; h < 5; h++){
    float s = 0.f;
    #pragma unroll
    for (int q = 0; q < 8; q++){
      float4 w = wv[h*8 + q];
      s += r[q].x*w.x + r[q].y*w.y + r[q].z*w.z + r[q].w*w.w;
    }
    dots[h] = s;
  }
  int d = dst[e];
  int slot = rowptr[d] + atomicAdd(&cursor[d], 1);
  srccsr[slot] = src[e];
  float4 o; o.x = dots[0]; o.y = dots[1]; o.z = dots[2]; o.w = dots[3];
  *(float4*)(edot1 + (size_t)slot*4) = o;
  edot2[slot] = dots[4];
}

// ---------------- MFMA bf16 GEMM, 128x64 tile ----------------
// MODE 0: A fp32 [NN x KTOT], convert to bf16 in staging (gemm1).
// MODE 1: A bf16 [NN x KTOT], BN(from raw stats)+ReLU in staging (gemm2).
// Bt n-major bf16. blockIdx.y = head. out bf16 [NN x HGRID*64], alsrc/aldst [NN x HGRID].
template<int KTOT, int MODE, int HGRID>
__global__ __launch_bounds__(256) void gemm_mfma(const void* __restrict__ Ap,
    const unsigned short* __restrict__ Bt,
    const float* __restrict__ cs, const float* __restrict__ csq,
    const float* __restrict__ g, const float* __restrict__ b,
    const float* __restrict__ a_s, const float* __restrict__ a_d,
    unsigned short* __restrict__ out, float* __restrict__ alsrc, float* __restrict__ aldst){
  __shared__ unsigned short As[128*136];
  __shared__ unsigned short Bs[64*136];
  __shared__ float s_scale[KTOT], s_shift[KTOT];
  const int tid = threadIdx.x;
  const int w = tid >> 6, lane = tid & 63;
  const int c = lane & 15, gq = lane >> 4;
  const int m0 = blockIdx.x * 128;
  const int head = blockIdx.y;
  const int NCOLT = HGRID * 64;
  if constexpr (MODE == 1){
    if (tid < KTOT){
      float mu  = cs[tid]  * (1.f/NN);
      float var = csq[tid] * (1.f/NN) - mu*mu;
      float rs  = rsqrtf(var + 1e-5f);
      float sc  = rs * g[tid];
      s_scale[tid] = sc;
      s_shift[tid] = b[tid] - mu*sc;
    }
    __syncthreads();
  }
  f32x4 acc[2][4];
  #pragma unroll
  for (int mt = 0; mt < 2; mt++)
    #pragma unroll
    for (int nt = 0; nt < 4; nt++) acc[mt][nt] = (f32x4){0.f,0.f,0.f,0.f};

  for (int kp = 0; kp < KTOT; kp += 128){
    if constexpr (MODE == 0){
      const float* Af = (const float*)Ap;
      #pragma unroll
      for (int q = 0; q < 16; q++){
        int ch = tid*16 + q;                // 4096 chunks of 4 fp32
        int r = ch >> 5, off = (ch & 31)*4;
        int grow = m0 + r;
        ushort4 o;
        if (grow < NN){
          float4 v = *(const float4*)(Af + (size_t)grow*KTOT + kp + off);
          o.x = f2b(v.x); o.y = f2b(v.y); o.z = f2b(v.z); o.w = f2b(v.w);
        } else o = make_ushort4(0,0,0,0);
        *(ushort4*)&As[r*136 + off] = o;
      }
    } else {
      const unsigned short* Ab = (const unsigned short*)Ap;
      #pragma unroll
      for (int q = 0; q < 16; q++){
        int ch = tid*16 + q;
        int r = ch >> 5, off = (ch & 31)*4;
        int grow = m0 + r;
        ushort4 o;
        if (grow < NN){
          ushort4 v = *(const ushort4*)(Ab + (size_t)grow*KTOT + kp + off);
          float4 sc = *(const float4*)&s_scale[kp + off];
          float4 sh = *(const float4*)&s_shift[kp + off];
          o.x = f2b(fmaxf(fmaf(b2f(v.x), sc.x, sh.x), 0.f));
          o.y = f2b(fmaxf(fmaf(b2f(v.y), sc.y, sh.y), 0.f));
          o.z = f2b(fmaxf(fmaf(b2f(v.z), sc.z, sh.z), 0.f));
          o.w = f2b(fmaxf(fmaf(b2f(v.w), sc.w, sh.w), 0.f));
        } else o = make_ushort4(0,0,0,0);
        *(ushort4*)&As[r*136 + off] = o;
      }
    }
    #pragma unroll
    for (int q = 0; q < 4; q++){
      int ch = tid*4 + q;                   // 1024 chunks of 8 bf16
      int n = ch >> 4, off = (ch & 15)*8;
      *(ulonglong2*)&Bs[n*136 + off] = *(const ulonglong2*)(Bt + (size_t)(head*64 + n)*KTOT + kp + off);
    }
    __syncthreads();
    #pragma unroll
    for (int k0 = 0; k0 < 128; k0 += 32){
      b16x8 afr[2], bfr[4];
      #pragma unroll
      for (int mt = 0; mt < 2; mt++)
        afr[mt] = *(const b16x8*)&As[(w*32 + mt*16 + c)*136 + k0 + gq*8];
      #pragma unroll
      for (int nt = 0; nt < 4; nt++)
        bfr[nt] = *(const b16x8*)&Bs[(nt*16 + c)*136 + k0 + gq*8];
      #pragma unroll
      for (int mt = 0; mt < 2; mt++)
        #pragma unroll
        for (int nt = 0; nt < 4; nt++)
          acc[mt][nt] = __builtin_amdgcn_mfma_f32_16x16x32_bf16(afr[mt], bfr[nt], acc[mt][nt], 0, 0, 0);
    }
    __syncthreads();
  }
  float asv[4], adv[4];
  #pragma unroll
  for (int nt = 0; nt < 4; nt++){
    asv[nt] = a_s[head*64 + nt*16 + c];
    adv[nt] = a_d[head*64 + nt*16 + c];
  }
  #pragma unroll
  for (int mt = 0; mt < 2; mt++){
    int base_row = m0 + w*32 + mt*16 + gq*4;
    #pragma unroll
    for (int r = 0; r < 4; r++){
      int row = base_row + r;
      float ps = 0.f, pd = 0.f;
      #pragma unroll
      for (int nt = 0; nt < 4; nt++){
        ps += acc[mt][nt][r] * asv[nt];
        pd += acc[mt][nt][r] * adv[nt];
      }
      ps = wsum16(ps); pd = wsum16(pd);
      if (row < NN){
        if (c == 0){
          alsrc[(size_t)row*HGRID + head] = ps;
          aldst[(size_t)row*HGRID + head] = pd;
        }
        #pragma unroll
        for (int nt = 0; nt < 4; nt++)
          out[(size_t)row*NCOLT + head*64 + nt*16 + c] = f2b(acc[mt][nt][r]);
      }
    }
  }
}

// ---------------- segment softmax + bf16 weighted gather ----------------
// H=4: out is bf16 (h1). H=1: out is fp32 (h2).
template<int H>
__global__ __launch_bounds__(256) void agg_kernel(const int* __restrict__ rowptr,
    const int* __restrict__ src_csr, const float* __restrict__ edot,
    const float* __restrict__ al_src, const float* __restrict__ al_dst,
    const unsigned short* __restrict__ xsb, const float* __restrict__ bias,
    unsigned short* __restrict__ outb, float* __restrict__ outf){
  constexpr int CH = 128;
  __shared__ float s_e_all[4][CH*H];
  __shared__ int   s_src_all[4][CH];
  const int wid  = threadIdx.x >> 6;
  const int lane = threadIdx.x & 63;
  const int i = blockIdx.x*4 + wid;
  float* s_e  = s_e_all[wid];
  int*   s_src = s_src_all[wid];
  const int r0 = rowptr[i];
  const int d  = rowptr[i+1] - r0;
  float ad[H], asi[H];
  #pragma unroll
  for (int h = 0; h < H; h++){ ad[h] = al_dst[(size_t)i*H+h]; asi[h] = al_src[(size_t)i*H+h]; }
  float sesum[H], m[H];
  #pragma unroll
  for (int h = 0; h < H; h++){ sesum[h] = 0.f; m[h] = -1e30f; }
  for (int t = lane; t < d; t += 64){
    int s = r0 + t;
    int sn = src_csr[s];
    if (t < CH) s_src[t] = sn;
    float al[H];
    if constexpr (H == 4){
      float4 av = *(const float4*)(al_src + (size_t)sn*4);
      float4 ev = *(const float4*)(edot + (size_t)s*4);
      al[0]=av.x+ad[0]+ev.x; al[1]=av.y+ad[1]+ev.y; al[2]=av.z+ad[2]+ev.z; al[3]=av.w+ad[3]+ev.w;
      sesum[0]+=ev.x; sesum[1]+=ev.y; sesum[2]+=ev.z; sesum[3]+=ev.w;
    } else {
      float ev = edot[s];
      al[0] = al_src[sn] + ad[0] + ev;
      sesum[0] += ev;
    }
    #pragma unroll
    for (int h = 0; h < H; h++){
      float a = al[h]; a = a > 0.f ? a : 0.2f*a;
      if (t < CH) s_e[t*H+h] = a;
      m[h] = fmaxf(m[h], a);
    }
  }
  float invd = (d > 0) ? 1.f/(float)d : 0.f;
  float sa[H];
  #pragma unroll
  for (int h = 0; h < H; h++){
    sesum[h] = wsum64(sesum[h]);
    m[h] = wmax64(m[h]);
    float a = asi[h] + ad[h] + sesum[h]*invd;
    sa[h] = a > 0.f ? a : 0.2f*a;
    m[h] = fmaxf(m[h], sa[h]);
  }
  float acc[H], dpart[H];
  #pragma unroll
  for (int h = 0; h < H; h++){ acc[h] = 0.f; dpart[h] = 0.f; }
  int c0 = 0;
  while (c0 < d){
    int cl = min(CH, d - c0);
    if (c0 > 0){
      for (int t = lane; t < cl; t += 64){
        int s = r0 + c0 + t;
        int sn = src_csr[s];
        s_src[t] = sn;
        if constexpr (H == 4){
          float4 av = *(const float4*)(al_src + (size_t)sn*4);
          float4 ev = *(const float4*)(edot + (size_t)s*4);
          float a0=av.x+ad[0]+ev.x, a1=av.y+ad[1]+ev.y, a2=av.z+ad[2]+ev.z, a3=av.w+ad[3]+ev.w;
          s_e[t*4+0]=a0>0.f?a0:0.2f*a0; s_e[t*4+1]=a1>0.f?a1:0.2f*a1;
          s_e[t*4+2]=a2>0.f?a2:0.2f*a2; s_e[t*4+3]=a3>0.f?a3:0.2f*a3;
        } else {
          float a = al_src[sn] + ad[0] + edot[s];
          s_e[t] = a > 0.f ? a : 0.2f*a;
        }
      }
    }
    for (int t = lane; t < cl; t += 64){
      #pragma unroll
      for (int h = 0; h < H; h++){
        float e = __expf(s_e[t*H+h] - m[h]);
        s_e[t*H+h] = e;
        dpart[h] += e;
      }
    }
    __builtin_amdgcn_wave_barrier();
    if constexpr (H == 4){
      const int hd = lane >> 4;
      for (int t = 0; t < cl; t++){
        int sn = s_src[t];
        float w = s_e[t*4 + hd];
        ushort4 u = *(const ushort4*)(xsb + (size_t)sn*256 + 4*lane);
        acc[0] += w*b2f(u.x); acc[1] += w*b2f(u.y); acc[2] += w*b2f(u.z); acc[3] += w*b2f(u.w);
      }
    } else {
      for (int t = 0; t < cl; t++){
        acc[0] += s_e[t] * b2f(xsb[(size_t)s_src[t]*64 + lane]);
      }
    }
    c0 += CH;
  }
  float es[H];
  #pragma unroll
  for (int h = 0; h < H; h++) es[h] = __expf(sa[h] - m[h]);
  if (lane == 0){
    #pragma unroll
    for (int h = 0; h < H; h++) dpart[h] += es[h];
  }
  if constexpr (H == 4){
    const int hd = lane >> 4;
    ushort4 u = *(const ushort4*)(xsb + (size_t)i*256 + 4*lane);
    float w = es[hd];
    acc[0] += w*b2f(u.x); acc[1] += w*b2f(u.y); acc[2] += w*b2f(u.z); acc[3] += w*b2f(u.w);
  } else {
    acc[0] += es[0] * b2f(xsb[(size_t)i*64 + lane]);
  }
  float denom[H];
  #pragma unroll
  for (int h = 0; h < H; h++) denom[h] = wsum64(dpart[h]);
  if constexpr (H == 4){
    const int hd = lane >> 4;
    float inv = 1.f / denom[hd];
    float4 bv = *(const float4*)(bias + 4*lane);
    ushort4 o;
    o.x = f2b(acc[0]*inv + bv.x); o.y = f2b(acc[1]*inv + bv.y);
    o.z = f2b(acc[2]*inv + bv.z); o.w = f2b(acc[3]*inv + bv.w);
    *(ushort4*)(outb + (size_t)i*256 + 4*lane) = o;
  } else {
    outf[(size_t)i*64 + lane] = acc[0]/denom[0] + bias[lane];
  }
}

// ---------------- BN stats ----------------
__global__ __launch_bounds__(256) void bn_stats_b16_kernel(const unsigned short* __restrict__ h,
    float* __restrict__ cs, float* __restrict__ csq){
  int col = threadIdx.x;                     // F = 256
  float s = 0.f, s2 = 0.f;
  for (int r = blockIdx.x; r < NN; r += 256){
    float v = b2f(h[(size_t)r*256 + col]);
    s += v; s2 += v*v;
  }
  atomicAdd(&cs[col], s);
  atomicAdd(&csq[col], s2);
}

__global__ __launch_bounds__(256) void bn_stats_f32_kernel(const float* __restrict__ h,
    float* __restrict__ cs, float* __restrict__ csq){
  int col = threadIdx.x & 63;                // F = 64, 4 rows per block pass
  int ro  = threadIdx.x >> 6;
  float s = 0.f, s2 = 0.f;
  for (int r = blockIdx.x*4 + ro; r < NN; r += 1024){
    float v = h[(size_t)r*64 + col];
    s += v; s2 += v*v;
  }
  atomicAdd(&cs[col], s);
  atomicAdd(&csq[col], s2);
}

// ---------------- pooling ----------------
__global__ __launch_bounds__(256) void gate_kernel(const float* __restrict__ h,
    const float* __restrict__ cs, const float* __restrict__ csq,
    const float* __restrict__ g2, const float* __restrict__ b2,
    const float* __restrict__ Wg, const float* __restrict__ bg,
    float* __restrict__ hn, float* __restrict__ gate){
  int wid = threadIdx.x >> 6, lane = threadIdx.x & 63;
  int n = blockIdx.x*4 + wid;
  float mu  = cs[lane]  * (1.f/NN);
  float var = csq[lane] * (1.f/NN) - mu*mu;
  float rs  = rsqrtf(var + 1e-5f);
  float sc  = rs * g2[lane];
  float sh  = b2[lane] - mu*sc;
  float v = h[(size_t)n*64 + lane];
  float xx = fmaxf(fmaf(v, sc, sh), 0.f);
  hn[(size_t)n*64 + lane] = xx;
  float p = wsum64(xx * Wg[lane]);
  if (lane == 0) gate[n] = p + bg[0];
}

__global__ __launch_bounds__(256) void pool_kernel(const int* __restrict__ batch,
    const float* __restrict__ gate, const float* __restrict__ hn, float* __restrict__ out){
  __shared__ float red[256];
  __shared__ float wred_[4];
  __shared__ int seb[2];
  int b = blockIdx.x, tid = threadIdx.x;
  if (tid < 2){
    int target = b + tid;
    int lo = 0, hi = NN;
    while (lo < hi){ int mid = (lo+hi) >> 1; if (batch[mid] < target) lo = mid+1; else hi = mid; }
    seb[tid] = lo;
  }
  __syncthreads();
  int s = seb[0], e = seb[1];
  if (e <= s){ if (tid < 64) out[b*64 + tid] = 0.f; return; }
  float mloc = -1e30f;
  for (int n = s + tid; n < e; n += 256) mloc = fmaxf(mloc, gate[n]);
  mloc = wmax64(mloc);
  if ((tid & 63) == 0) red[tid >> 6] = mloc;
  __syncthreads();
  float m = fmaxf(fmaxf(red[0], red[1]), fmaxf(red[2], red[3]));
  __syncthreads();
  int col = tid & 63, ro = tid >> 6;
  float acc = 0.f, wp = 0.f;
  for (int n = s + ro; n < e; n += 4){
    float w = __expf(gate[n] - m);
    if (col == 0) wp += w;
    acc += w * hn[(size_t)n*64 + col];
  }
  red[tid] = acc;
  if (col == 0) wred_[ro] = wp;
  __syncthreads();
  if (ro == 0){
    float tot = red[col] + red[64+col] + red[128+col] + red[192+col];
    float wsm = wred_[0] + wred_[1] + wred_[2] + wred_[3];
    out[b*64 + col] = tot / wsm;
  }
}

// ---------------- host ----------------
extern "C" void kernel_launch(void* const* d_in, const int* in_sizes, int n_in,
                              void* d_out, int out_size, void* d_ws, size_t ws_size,
                              hipStream_t stream){
  const float* x     = (const float*)d_in[0];
  const float* ea    = (const float*)d_in[1];
  const int*   ei    = (const int*)d_in[2];
  const int*   batch = (const int*)d_in[3];
  const float* W1    = (const float*)d_in[4];
  const float* We1   = (const float*)d_in[5];
  const float* as1   = (const float*)d_in[6];
  const float* ad1   = (const float*)d_in[7];
  const float* ae1   = (const float*)d_in[8];
  const float* bias1 = (const float*)d_in[9];
  const float* g1    = (const float*)d_in[10];
  const float* b1    = (const float*)d_in[11];
  const float* W2    = (const float*)d_in[12];
  const float* We2   = (const float*)d_in[13];
  const float* as2   = (const float*)d_in[14];
  const float* ad2   = (const float*)d_in[15];
  const float* ae2   = (const float*)d_in[16];
  const float* bias2 = (const float*)d_in[17];
  const float* g2    = (const float*)d_in[18];
  const float* b2    = (const float*)d_in[19];
  const float* Wg    = (const float*)d_in[20];
  const float* bg    = (const float*)d_in[21];
  const int* srcI = ei;
  const int* dstI = ei + EE;

  char* ws = (char*)d_ws;
  int*   deg    = (int*)(ws + 0);          // memset region start
  int*   cursor = (int*)(ws + 120064);
  float* stats  = (float*)(ws + 240128);   // cs1@0 csq1@256 cs2@512 csq2@576
  int*   rowptr = (int*)(ws + 244224);
  int*   srccsr = (int*)(ws + 364288);
  float* wae    = (float*)(ws + 2284288);
  unsigned short* W1t = (unsigned short*)(ws + 2285056);
  unsigned short* W2t = (unsigned short*)(ws + 2350592);
  float* alsrc  = (float*)(ws + 2383360);
  float* aldst  = (float*)(ws + 2863360);
  float* gateb  = (float*)(ws + 3343360);
  float* edot1  = (float*)(ws + 3463424);   // E*4 f32
  float* edot2  = (float*)(ws + 11143424);  // E f32
  unsigned short* xs1b = (unsigned short*)(ws + 13063424); // 30000*256 bf16
  unsigned short* h1b  = (unsigned short*)(ws + 28423424); // 30000*256 bf16
  unsigned short* xs2b = (unsigned short*)(ws + 43783424); // 30000*64 bf16
  float* h2     = (float*)(ws + 47623424);  // 30000*64 f32
  float* hn     = (float*)(ws + 55303424);  // 30000*64 f32
  // total ~63 MB

  (void)hipMemsetAsync(ws, 0, 244224, stream);   // deg, cursor, stats

  hist_kernel<<<1875, 256, 0, stream>>>(dstI, deg);
  scan_kernel<<<1, 1024, 0, stream>>>(deg, rowptr);
  prep_kernel<<<2, 256, 0, stream>>>(W1, W2, We1, ae1, We2, ae2, W1t, W2t, wae);
  edot_scatter_kernel<<<1875, 256, 0, stream>>>(ea, wae, srcI, dstI, rowptr, cursor,
                                                srccsr, edot1, edot2);

  // ---- layer 1 (H=4): MFMA GEMM [30000x128]@[128x256], fp32 A converted in staging ----
  gemm_mfma<128, 0, 4><<<dim3(235, 4), 256, 0, stream>>>(
      x, W1t, nullptr, nullptr, nullptr, nullptr, as1, ad1, xs1b, alsrc, aldst);
  agg_kernel<4><<<7500, 256, 0, stream>>>(rowptr, srccsr, edot1, alsrc, aldst, xs1b, bias1, h1b, nullptr);
  bn_stats_b16_kernel<<<256, 256, 0, stream>>>(h1b, stats + 0, stats + 256);

  // ---- layer 2 (H=1): BN(from stats)+ReLU fused into MFMA GEMM A-staging ----
  gemm_mfma<256, 1, 1><<<dim3(235, 1), 256, 0, stream>>>(
      h1b, W2t, stats + 0, stats + 256, g1, b1, as2, ad2, xs2b, alsrc, aldst);
  agg_kernel<1><<<7500, 256, 0, stream>>>(rowptr, srccsr, edot2, alsrc, aldst, xs2b, bias2, nullptr, h2);
  bn_stats_f32_kernel<<<256, 256, 0, stream>>>(h2, stats + 512, stats + 576);

  // ---- pool (BN2 applied inline in gate; graph ranges via binary search in pool) ----
  gate_kernel<<<7500, 256, 0, stream>>>(h2, stats + 512, stats + 576, g2, b2, Wg, bg, hn, gateb);
  pool_kernel<<<64, 256, 0, stream>>>(batch, gateb, hn, (float*)d_out);
}

// Round 5
// 420.734 us; speedup vs baseline: 1.3049x; 1.1500x over previous
//
#include <hip/hip_runtime.h>
#include <math.h>

#define NN 30000
#define EE 480000
#define BB 64

typedef __bf16 b16x8 __attribute__((ext_vector_type(8)));
typedef float  f32x4 __attribute__((ext_vector_type(4)));
typedef unsigned short u16x8 __attribute__((ext_vector_type(8)));

// ---------------- helpers ----------------
__device__ __forceinline__ float wsum64(float v){
  #pragma unroll
  for (int m = 32; m >= 1; m >>= 1) v += __shfl_xor(v, m, 64);
  return v;
}
__device__ __forceinline__ float wmax64(float v){
  #pragma unroll
  for (int m = 32; m >= 1; m >>= 1) v = fmaxf(v, __shfl_xor(v, m, 64));
  return v;
}
__device__ __forceinline__ float wsum16(float v){
  #pragma unroll
  for (int m = 1; m < 16; m <<= 1) v += __shfl_xor(v, m, 64);
  return v;
}
__device__ __forceinline__ unsigned short f2b(float f){   // fp32 -> bf16 RNE
  union { float f; unsigned u; } v; v.f = f;
  unsigned r = v.u + 0x7fffu + ((v.u >> 16) & 1u);
  return (unsigned short)(r >> 16);
}
__device__ __forceinline__ float b2f(unsigned short u){
  union { unsigned u; float f; } v; v.u = ((unsigned)u) << 16;
  return v.f;
}

// ---------------- CSR build ----------------
__global__ void hist_kernel(const int* __restrict__ dst, int* __restrict__ deg){
  int e = blockIdx.x*256 + threadIdx.x;
  if (e < EE) atomicAdd(&deg[dst[e]], 1);
}

__global__ __launch_bounds__(1024) void scan_kernel(const int* __restrict__ deg, int* __restrict__ rowptr){
  __shared__ int s[1024];
  int tid = threadIdx.x;
  const int PER = 30;
  int base = tid * PER;
  int sum = 0;
  for (int j = 0; j < PER; j++){ int idx = base+j; if (idx < NN) sum += deg[idx]; }
  s[tid] = sum; __syncthreads();
  for (int off = 1; off < 1024; off <<= 1){
    int v = 0;
    if (tid >= off) v = s[tid-off];
    __syncthreads();
    s[tid] += v;
    __syncthreads();
  }
  int run = s[tid] - sum;
  for (int j = 0; j < PER; j++){
    int idx = base+j;
    if (idx < NN){ rowptr[idx] = run; run += deg[idx]; }
  }
  if (tid == 1023) rowptr[NN] = s[1023];
}

// ---------------- prep: W transposes (bf16) + wae dots ----------------
__global__ void prep_kernel(const float* __restrict__ W1, const float* __restrict__ W2,
                            const float* __restrict__ We1, const float* __restrict__ ae1,
                            const float* __restrict__ We2, const float* __restrict__ ae2,
                            unsigned short* __restrict__ W1t, unsigned short* __restrict__ W2t,
                            float* __restrict__ wae){
  int t = threadIdx.x;
  if (blockIdx.x == 0){
    for (int k = 0; k < 128; k++) W1t[t*128 + k] = f2b(W1[k*256 + t]);
    if (t < 64){
      for (int k = 0; k < 256; k++) W2t[t*256 + k] = f2b(W2[k*64 + t]);
    }
  } else {
    if (t < 128){
      int h = t >> 5, k = t & 31;
      float s = 0.f;
      for (int f = 0; f < 64; f++) s += We1[k*256 + h*64 + f] * ae1[h*64 + f];
      wae[h*32 + k] = s;
    } else if (t < 160){
      int k = t - 128;
      float s = 0.f;
      for (int f = 0; f < 64; f++) s += We2[k*64 + f] * ae2[f];
      wae[128 + k] = s;
    }
  }
}

// ---------------- fused edge pass: 8 lanes per edge, coalesced ea reads ----------------
__global__ __launch_bounds__(256) void edot_scatter_kernel(const float* __restrict__ ea,
    const float* __restrict__ wae, const int* __restrict__ src, const int* __restrict__ dst,
    const int* __restrict__ rowptr, int* __restrict__ cursor,
    int* __restrict__ srccsr, float* __restrict__ edot1, float* __restrict__ edot2){
  __shared__ float s_w[160];
  if (threadIdx.x < 160) s_w[threadIdx.x] = wae[threadIdx.x];
  __syncthreads();
  const int il = threadIdx.x & 7;
  const int e = blockIdx.x*32 + (threadIdx.x >> 3);
  if (e >= EE) return;
  float4 v = *(const float4*)(ea + (size_t)e*32 + il*4);   // 1KB per wave, coalesced
  float dots[5];
  #pragma unroll
  for (int h = 0; h < 5; h++){
    float4 w = *(const float4*)&s_w[h*32 + il*4];
    dots[h] = v.x*w.x + v.y*w.y + v.z*w.z + v.w*w.w;
  }
  #pragma unroll
  for (int m = 1; m < 8; m <<= 1)
    #pragma unroll
    for (int h = 0; h < 5; h++) dots[h] += __shfl_xor(dots[h], m, 64);
  if (il == 0){
    int dd = dst[e];
    int slot = rowptr[dd] + atomicAdd(&cursor[dd], 1);
    srccsr[slot] = src[e];
    float4 o; o.x = dots[0]; o.y = dots[1]; o.z = dots[2]; o.w = dots[3];
    *(float4*)(edot1 + (size_t)slot*4) = o;
    edot2[slot] = dots[4];
  }
}

// ---------------- GEMM1: MFMA bf16, 128 rows, all 4 heads looped in-block ----------------
__global__ __launch_bounds__(256) void gemm1_mfma(const float* __restrict__ x,
    const unsigned short* __restrict__ Bt, const float* __restrict__ a_s, const float* __restrict__ a_d,
    unsigned short* __restrict__ out, float* __restrict__ alsrc, float* __restrict__ aldst){
  __shared__ unsigned short As[128*136];
  __shared__ unsigned short Bs[64*136];
  const int tid = threadIdx.x;
  const int w = tid >> 6, lane = tid & 63;
  const int c = lane & 15, gq = lane >> 4;
  const int m0 = blockIdx.x * 128;
  // stage A once (fp32 -> bf16)
  #pragma unroll
  for (int q = 0; q < 16; q++){
    int ch = tid*16 + q;
    int r = ch >> 5, off = (ch & 31)*4;
    int grow = m0 + r;
    ushort4 o;
    if (grow < NN){
      float4 v = *(const float4*)(x + (size_t)grow*128 + off);
      o.x = f2b(v.x); o.y = f2b(v.y); o.z = f2b(v.z); o.w = f2b(v.w);
    } else o = make_ushort4(0,0,0,0);
    *(ushort4*)&As[r*136 + off] = o;
  }
  #pragma unroll
  for (int q = 0; q < 4; q++){
    int ch = tid*4 + q;
    int n = ch >> 4, off = (ch & 15)*8;
    *(ulonglong2*)&Bs[n*136 + off] = *(const ulonglong2*)(Bt + (size_t)n*128 + off);
  }
  __syncthreads();
  for (int head = 0; head < 4; head++){
    f32x4 acc[2][4];
    #pragma unroll
    for (int mt = 0; mt < 2; mt++)
      #pragma unroll
      for (int nt = 0; nt < 4; nt++) acc[mt][nt] = (f32x4){0.f,0.f,0.f,0.f};
    #pragma unroll
    for (int k0 = 0; k0 < 128; k0 += 32){
      b16x8 afr[2], bfr[4];
      #pragma unroll
      for (int mt = 0; mt < 2; mt++)
        afr[mt] = *(const b16x8*)&As[(w*32 + mt*16 + c)*136 + k0 + gq*8];
      #pragma unroll
      for (int nt = 0; nt < 4; nt++)
        bfr[nt] = *(const b16x8*)&Bs[(nt*16 + c)*136 + k0 + gq*8];
      #pragma unroll
      for (int mt = 0; mt < 2; mt++)
        #pragma unroll
        for (int nt = 0; nt < 4; nt++)
          acc[mt][nt] = __builtin_amdgcn_mfma_f32_16x16x32_bf16(afr[mt], bfr[nt], acc[mt][nt], 0, 0, 0);
    }
    __syncthreads();                    // everyone done reading Bs
    if (head < 3){                      // restage next head's B (overlaps epilogue)
      #pragma unroll
      for (int q = 0; q < 4; q++){
        int ch = tid*4 + q;
        int n = ch >> 4, off = (ch & 15)*8;
        *(ulonglong2*)&Bs[n*136 + off] = *(const ulonglong2*)(Bt + (size_t)((head+1)*64 + n)*128 + off);
      }
    }
    float asv[4], adv[4];
    #pragma unroll
    for (int nt = 0; nt < 4; nt++){
      asv[nt] = a_s[head*64 + nt*16 + c];
      adv[nt] = a_d[head*64 + nt*16 + c];
    }
    #pragma unroll
    for (int mt = 0; mt < 2; mt++){
      int base_row = m0 + w*32 + mt*16 + gq*4;
      #pragma unroll
      for (int r = 0; r < 4; r++){
        int row = base_row + r;
        float ps = 0.f, pd = 0.f;
        #pragma unroll
        for (int nt = 0; nt < 4; nt++){
          ps += acc[mt][nt][r] * asv[nt];
          pd += acc[mt][nt][r] * adv[nt];
        }
        ps = wsum16(ps); pd = wsum16(pd);
        if (row < NN){
          if (c == 0){
            alsrc[(size_t)row*4 + head] = ps;
            aldst[(size_t)row*4 + head] = pd;
          }
          #pragma unroll
          for (int nt = 0; nt < 4; nt++)
            out[(size_t)row*256 + head*64 + nt*16 + c] = f2b(acc[mt][nt][r]);
        }
      }
    }
    if (head < 3) __syncthreads();
  }
}

// ---------------- GEMM2: MFMA bf16, BN(from raw stats)+ReLU fused on A ----------------
__global__ __launch_bounds__(256) void gemm2_mfma(const unsigned short* __restrict__ Ab,
    const unsigned short* __restrict__ Bt,
    const float* __restrict__ cs, const float* __restrict__ csq,
    const float* __restrict__ g, const float* __restrict__ b,
    const float* __restrict__ a_s, const float* __restrict__ a_d,
    unsigned short* __restrict__ out, float* __restrict__ alsrc, float* __restrict__ aldst){
  __shared__ unsigned short As[128*136];
  __shared__ unsigned short Bs[64*136];
  __shared__ float s_scale[256], s_shift[256];
  const int tid = threadIdx.x;
  const int w = tid >> 6, lane = tid & 63;
  const int c = lane & 15, gq = lane >> 4;
  const int m0 = blockIdx.x * 128;
  if (tid < 256){
    float mu  = cs[tid]  * (1.f/NN);
    float var = csq[tid] * (1.f/NN) - mu*mu;
    float rs  = rsqrtf(var + 1e-5f);
    float sc  = rs * g[tid];
    s_scale[tid] = sc;
    s_shift[tid] = b[tid] - mu*sc;
  }
  __syncthreads();
  f32x4 acc[2][4];
  #pragma unroll
  for (int mt = 0; mt < 2; mt++)
    #pragma unroll
    for (int nt = 0; nt < 4; nt++) acc[mt][nt] = (f32x4){0.f,0.f,0.f,0.f};
  for (int kp = 0; kp < 256; kp += 128){
    #pragma unroll
    for (int q = 0; q < 16; q++){
      int ch = tid*16 + q;
      int r = ch >> 5, off = (ch & 31)*4;
      int grow = m0 + r;
      ushort4 o;
      if (grow < NN){
        ushort4 v = *(const ushort4*)(Ab + (size_t)grow*256 + kp + off);
        float4 sc = *(const float4*)&s_scale[kp + off];
        float4 sh = *(const float4*)&s_shift[kp + off];
        o.x = f2b(fmaxf(fmaf(b2f(v.x), sc.x, sh.x), 0.f));
        o.y = f2b(fmaxf(fmaf(b2f(v.y), sc.y, sh.y), 0.f));
        o.z = f2b(fmaxf(fmaf(b2f(v.z), sc.z, sh.z), 0.f));
        o.w = f2b(fmaxf(fmaf(b2f(v.w), sc.w, sh.w), 0.f));
      } else o = make_ushort4(0,0,0,0);
      *(ushort4*)&As[r*136 + off] = o;
    }
    #pragma unroll
    for (int q = 0; q < 4; q++){
      int ch = tid*4 + q;
      int n = ch >> 4, off = (ch & 15)*8;
      *(ulonglong2*)&Bs[n*136 + off] = *(const ulonglong2*)(Bt + (size_t)n*256 + kp + off);
    }
    __syncthreads();
    #pragma unroll
    for (int k0 = 0; k0 < 128; k0 += 32){
      b16x8 afr[2], bfr[4];
      #pragma unroll
      for (int mt = 0; mt < 2; mt++)
        afr[mt] = *(const b16x8*)&As[(w*32 + mt*16 + c)*136 + k0 + gq*8];
      #pragma unroll
      for (int nt = 0; nt < 4; nt++)
        bfr[nt] = *(const b16x8*)&Bs[(nt*16 + c)*136 + k0 + gq*8];
      #pragma unroll
      for (int mt = 0; mt < 2; mt++)
        #pragma unroll
        for (int nt = 0; nt < 4; nt++)
          acc[mt][nt] = __builtin_amdgcn_mfma_f32_16x16x32_bf16(afr[mt], bfr[nt], acc[mt][nt], 0, 0, 0);
    }
    __syncthreads();
  }
  float asv[4], adv[4];
  #pragma unroll
  for (int nt = 0; nt < 4; nt++){
    asv[nt] = a_s[nt*16 + c];
    adv[nt] = a_d[nt*16 + c];
  }
  #pragma unroll
  for (int mt = 0; mt < 2; mt++){
    int base_row = m0 + w*32 + mt*16 + gq*4;
    #pragma unroll
    for (int r = 0; r < 4; r++){
      int row = base_row + r;
      float ps = 0.f, pd = 0.f;
      #pragma unroll
      for (int nt = 0; nt < 4; nt++){
        ps += acc[mt][nt][r] * asv[nt];
        pd += acc[mt][nt][r] * adv[nt];
      }
      ps = wsum16(ps); pd = wsum16(pd);
      if (row < NN){
        if (c == 0){
          alsrc[row] = ps;
          aldst[row] = pd;
        }
        #pragma unroll
        for (int nt = 0; nt < 4; nt++)
          out[(size_t)row*64 + nt*16 + c] = f2b(acc[mt][nt][r]);
      }
    }
  }
}

// ---------------- segment softmax + wide bf16 gather ----------------
// H=4: gather 2 edges concurrently (2 half-waves x 16B/lane); out bf16.
// H=1: gather 8 edges concurrently (8 groups x 16B/lane); out fp32.
template<int H>
__global__ __launch_bounds__(256) void agg_kernel(const int* __restrict__ rowptr,
    const int* __restrict__ src_csr, const float* __restrict__ edot,
    const float* __restrict__ al_src, const float* __restrict__ al_dst,
    const unsigned short* __restrict__ xsb, const float* __restrict__ bias,
    unsigned short* __restrict__ outb, float* __restrict__ outf){
  constexpr int CH = 128;
  __shared__ float s_e_all[4][CH*H];
  __shared__ int   s_src_all[4][CH];
  const int wid  = threadIdx.x >> 6;
  const int lane = threadIdx.x & 63;
  const int i = blockIdx.x*4 + wid;
  float* s_e  = s_e_all[wid];
  int*   s_src = s_src_all[wid];
  const int r0 = rowptr[i];
  const int d  = rowptr[i+1] - r0;
  float ad[H], asi[H];
  #pragma unroll
  for (int h = 0; h < H; h++){ ad[h] = al_dst[(size_t)i*H+h]; asi[h] = al_src[(size_t)i*H+h]; }
  // pass 1: leaky(alpha) -> LDS, running max, edot sum for self loop
  float sesum[H], m[H];
  #pragma unroll
  for (int h = 0; h < H; h++){ sesum[h] = 0.f; m[h] = -1e30f; }
  for (int t = lane; t < d; t += 64){
    int s = r0 + t;
    int sn = src_csr[s];
    if (t < CH) s_src[t] = sn;
    float al[H];
    if constexpr (H == 4){
      float4 av = *(const float4*)(al_src + (size_t)sn*4);
      float4 ev = *(const float4*)(edot + (size_t)s*4);
      al[0]=av.x+ad[0]+ev.x; al[1]=av.y+ad[1]+ev.y; al[2]=av.z+ad[2]+ev.z; al[3]=av.w+ad[3]+ev.w;
      sesum[0]+=ev.x; sesum[1]+=ev.y; sesum[2]+=ev.z; sesum[3]+=ev.w;
    } else {
      float ev = edot[s];
      al[0] = al_src[sn] + ad[0] + ev;
      sesum[0] += ev;
    }
    #pragma unroll
    for (int h = 0; h < H; h++){
      float a = al[h]; a = a > 0.f ? a : 0.2f*a;
      if (t < CH) s_e[t*H+h] = a;
      m[h] = fmaxf(m[h], a);
    }
  }
  float invd = (d > 0) ? 1.f/(float)d : 0.f;
  float sa[H];
  #pragma unroll
  for (int h = 0; h < H; h++){
    sesum[h] = wsum64(sesum[h]);
    m[h] = wmax64(m[h]);
    float a = asi[h] + ad[h] + sesum[h]*invd;
    sa[h] = a > 0.f ? a : 0.2f*a;
    m[h] = fmaxf(m[h], sa[h]);
  }
  // pass 2: exp + wide unnormalized gather
  float acc8[8];
  #pragma unroll
  for (int j = 0; j < 8; j++) acc8[j] = 0.f;
  float dpart[H];
  #pragma unroll
  for (int h = 0; h < H; h++) dpart[h] = 0.f;
  const int half = lane >> 5, il5 = lane & 31;   // H==4 mapping
  const int grp  = lane >> 3, il3 = lane & 7;    // H==1 mapping
  int c0 = 0;
  while (c0 < d){
    int cl = min(CH, d - c0);
    if (c0 > 0){
      for (int t = lane; t < cl; t += 64){
        int s = r0 + c0 + t;
        int sn = src_csr[s];
        s_src[t] = sn;
        if constexpr (H == 4){
          float4 av = *(const float4*)(al_src + (size_t)sn*4);
          float4 ev = *(const float4*)(edot + (size_t)s*4);
          float a0=av.x+ad[0]+ev.x, a1=av.y+ad[1]+ev.y, a2=av.z+ad[2]+ev.z, a3=av.w+ad[3]+ev.w;
          s_e[t*4+0]=a0>0.f?a0:0.2f*a0; s_e[t*4+1]=a1>0.f?a1:0.2f*a1;
          s_e[t*4+2]=a2>0.f?a2:0.2f*a2; s_e[t*4+3]=a3>0.f?a3:0.2f*a3;
        } else {
          float a = al_src[sn] + ad[0] + edot[s];
          s_e[t] = a > 0.f ? a : 0.2f*a;
        }
      }
    }
    for (int t = lane; t < cl; t += 64){
      #pragma unroll
      for (int h = 0; h < H; h++){
        float e = __expf(s_e[t*H+h] - m[h]);
        s_e[t*H+h] = e;
        dpart[h] += e;
      }
    }
    __builtin_amdgcn_wave_barrier();
    if constexpr (H == 4){
      const int hd = il5 >> 3;
      for (int t = half; t < cl; t += 2){
        int sn = s_src[t];
        float wv = s_e[t*4 + hd];
        u16x8 u = *(const u16x8*)(xsb + (size_t)sn*256 + il5*8);   // 16B/lane
        #pragma unroll
        for (int j = 0; j < 8; j++) acc8[j] += wv * b2f(u[j]);
      }
    } else {
      for (int t = grp; t < cl; t += 8){
        int sn = s_src[t];
        float wv = s_e[t];
        u16x8 u = *(const u16x8*)(xsb + (size_t)sn*64 + il3*8);    // 16B/lane
        #pragma unroll
        for (int j = 0; j < 8; j++) acc8[j] += wv * b2f(u[j]);
      }
    }
    __builtin_amdgcn_wave_barrier();
    c0 += CH;
  }
  // self loop
  float es[H];
  #pragma unroll
  for (int h = 0; h < H; h++) es[h] = __expf(sa[h] - m[h]);
  if (lane == 0){
    #pragma unroll
    for (int h = 0; h < H; h++) dpart[h] += es[h];
  }
  if constexpr (H == 4){
    if (half == 0){
      float wv = es[il5 >> 3];
      u16x8 u = *(const u16x8*)(xsb + (size_t)i*256 + il5*8);
      #pragma unroll
      for (int j = 0; j < 8; j++) acc8[j] += wv * b2f(u[j]);
    }
  } else {
    if (grp == 0){
      float wv = es[0];
      u16x8 u = *(const u16x8*)(xsb + (size_t)i*64 + il3*8);
      #pragma unroll
      for (int j = 0; j < 8; j++) acc8[j] += wv * b2f(u[j]);
    }
  }
  float denom[H];
  #pragma unroll
  for (int h = 0; h < H; h++) denom[h] = wsum64(dpart[h]);
  if constexpr (H == 4){
    #pragma unroll
    for (int j = 0; j < 8; j++) acc8[j] += __shfl_xor(acc8[j], 32, 64);
    if (lane < 32){
      float inv = 1.f / denom[il5 >> 3];
      u16x8 o;
      #pragma unroll
      for (int j = 0; j < 8; j++) o[j] = f2b(acc8[j]*inv + bias[il5*8 + j]);
      *(u16x8*)(outb + (size_t)i*256 + il5*8) = o;
    }
  } else {
    #pragma unroll
    for (int j = 0; j < 8; j++){
      acc8[j] += __shfl_xor(acc8[j], 8, 64);
      acc8[j] += __shfl_xor(acc8[j], 16, 64);
      acc8[j] += __shfl_xor(acc8[j], 32, 64);
    }
    if (lane < 8){
      float inv = 1.f / denom[0];
      float4 o0, o1;
      o0.x = acc8[0]*inv + bias[il3*8+0]; o0.y = acc8[1]*inv + bias[il3*8+1];
      o0.z = acc8[2]*inv + bias[il3*8+2]; o0.w = acc8[3]*inv + bias[il3*8+3];
      o1.x = acc8[4]*inv + bias[il3*8+4]; o1.y = acc8[5]*inv + bias[il3*8+5];
      o1.z = acc8[6]*inv + bias[il3*8+6]; o1.w = acc8[7]*inv + bias[il3*8+7];
      *(float4*)(outf + (size_t)i*64 + il3*8)     = o0;
      *(float4*)(outf + (size_t)i*64 + il3*8 + 4) = o1;
    }
  }
}

// ---------------- BN stats ----------------
// bf16 h1 [NN x 256]: 8 rows/iter per block, 16B/lane
__global__ __launch_bounds__(256) void bn_stats_b16_kernel(const unsigned short* __restrict__ h,
    float* __restrict__ cs, float* __restrict__ csq){
  __shared__ float s_red[4][256], q_red[4][256];
  const int tid = threadIdx.x;
  const int wv = tid >> 6, lane = tid & 63;
  const int rg = lane >> 5, cg = lane & 31;
  float s8[8], q8[8];
  #pragma unroll
  for (int j = 0; j < 8; j++){ s8[j] = 0.f; q8[j] = 0.f; }
  for (int chunk = blockIdx.x; chunk < 3750; chunk += 256){
    int r = chunk*8 + wv*2 + rg;
    u16x8 u = *(const u16x8*)(h + (size_t)r*256 + cg*8);
    #pragma unroll
    for (int j = 0; j < 8; j++){
      float v = b2f(u[j]);
      s8[j] += v; q8[j] += v*v;
    }
  }
  #pragma unroll
  for (int j = 0; j < 8; j++){
    s8[j] += __shfl_xor(s8[j], 32, 64);
    q8[j] += __shfl_xor(q8[j], 32, 64);
  }
  if (lane < 32){
    #pragma unroll
    for (int j = 0; j < 8; j++){
      s_red[wv][cg*8 + j] = s8[j];
      q_red[wv][cg*8 + j] = q8[j];
    }
  }
  __syncthreads();
  if (tid < 256){
    float ts = s_red[0][tid] + s_red[1][tid] + s_red[2][tid] + s_red[3][tid];
    float tq = q_red[0][tid] + q_red[1][tid] + q_red[2][tid] + q_red[3][tid];
    atomicAdd(&cs[tid], ts);
    atomicAdd(&csq[tid], tq);
  }
}

__global__ __launch_bounds__(256) void bn_stats_f32_kernel(const float* __restrict__ h,
    float* __restrict__ cs, float* __restrict__ csq){
  int col = threadIdx.x & 63;
  int ro  = threadIdx.x >> 6;
  float s = 0.f, s2 = 0.f;
  for (int r = blockIdx.x*4 + ro; r < NN; r += 1024){
    float v = h[(size_t)r*64 + col];
    s += v; s2 += v*v;
  }
  atomicAdd(&cs[col], s);
  atomicAdd(&csq[col], s2);
}

// ---------------- pooling ----------------
__global__ __launch_bounds__(256) void gate_kernel(const float* __restrict__ h,
    const float* __restrict__ cs, const float* __restrict__ csq,
    const float* __restrict__ g2, const float* __restrict__ b2,
    const float* __restrict__ Wg, const float* __restrict__ bg,
    float* __restrict__ hn, float* __restrict__ gate){
  int wid = threadIdx.x >> 6, lane = threadIdx.x & 63;
  int n = blockIdx.x*4 + wid;
  float mu  = cs[lane]  * (1.f/NN);
  float var = csq[lane] * (1.f/NN) - mu*mu;
  float rs  = rsqrtf(var + 1e-5f);
  float sc  = rs * g2[lane];
  float sh  = b2[lane] - mu*sc;
  float v = h[(size_t)n*64 + lane];
  float xx = fmaxf(fmaf(v, sc, sh), 0.f);
  hn[(size_t)n*64 + lane] = xx;
  float p = wsum64(xx * Wg[lane]);
  if (lane == 0) gate[n] = p + bg[0];
}

__global__ __launch_bounds__(256) void pool_kernel(const int* __restrict__ batch,
    const float* __restrict__ gate, const float* __restrict__ hn, float* __restrict__ out){
  __shared__ float red[256];
  __shared__ float a_red[4][64], w_red[4];
  __shared__ int seb[2];
  int b = blockIdx.x, tid = threadIdx.x;
  int wv = tid >> 6, lane = tid & 63;
  if (tid < 2){
    int target = b + tid;
    int lo = 0, hi = NN;
    while (lo < hi){ int mid = (lo+hi) >> 1; if (batch[mid] < target) lo = mid+1; else hi = mid; }
    seb[tid] = lo;
  }
  __syncthreads();
  int s = seb[0], e = seb[1];
  if (e <= s){ if (tid < 64) out[b*64 + tid] = 0.f; return; }
  float mloc = -1e30f;
  for (int n = s + tid; n < e; n += 256) mloc = fmaxf(mloc, gate[n]);
  mloc = wmax64(mloc);
  if (lane == 0) red[wv] = mloc;
  __syncthreads();
  float m = fmaxf(fmaxf(red[0], red[1]), fmaxf(red[2], red[3]));
  // 16 rows per iteration, float4 per lane
  int rgrp = tid >> 4, cq = tid & 15;
  f32x4 acc = (f32x4){0.f,0.f,0.f,0.f};
  float wp = 0.f;
  for (int n = s + rgrp; n < e; n += 16){
    float wgt = __expf(gate[n] - m);
    float4 v = *(const float4*)(hn + (size_t)n*64 + cq*4);
    acc[0] += wgt*v.x; acc[1] += wgt*v.y; acc[2] += wgt*v.z; acc[3] += wgt*v.w;
    if (cq == 0) wp += wgt;
  }
  #pragma unroll
  for (int j = 0; j < 4; j++){
    acc[j] += __shfl_xor(acc[j], 16, 64);
    acc[j] += __shfl_xor(acc[j], 32, 64);
  }
  wp += __shfl_xor(wp, 16, 64);
  wp += __shfl_xor(wp, 32, 64);
  if (lane < 16){
    #pragma unroll
    for (int j = 0; j < 4; j++) a_red[wv][lane*4 + j] = acc[j];
  }
  if (lane == 0) w_red[wv] = wp;
  __syncthreads();
  if (tid < 64){
    float tot = a_red[0][tid] + a_red[1][tid] + a_red[2][tid] + a_red[3][tid];
    float wsm = w_red[0] + w_red[1] + w_red[2] + w_red[3];
    out[b*64 + tid] = tot / wsm;
  }
}

// ---------------- host ----------------
extern "C" void kernel_launch(void* const* d_in, const int* in_sizes, int n_in,
                              void* d_out, int out_size, void* d_ws, size_t ws_size,
                              hipStream_t stream){
  const float* x     = (const float*)d_in[0];
  const float* ea    = (const float*)d_in[1];
  const int*   ei    = (const int*)d_in[2];
  const int*   batch = (const int*)d_in[3];
  const float* W1    = (const float*)d_in[4];
  const float* We1   = (const float*)d_in[5];
  const float* as1   = (const float*)d_in[6];
  const float* ad1   = (const float*)d_in[7];
  const float* ae1   = (const float*)d_in[8];
  const float* bias1 = (const float*)d_in[9];
  const float* g1    = (const float*)d_in[10];
  const float* b1    = (const float*)d_in[11];
  const float* W2    = (const float*)d_in[12];
  const float* We2   = (const float*)d_in[13];
  const float* as2   = (const float*)d_in[14];
  const float* ad2   = (const float*)d_in[15];
  const float* ae2   = (const float*)d_in[16];
  const float* bias2 = (const float*)d_in[17];
  const float* g2    = (const float*)d_in[18];
  const float* b2    = (const float*)d_in[19];
  const float* Wg    = (const float*)d_in[20];
  const float* bg    = (const float*)d_in[21];
  const int* srcI = ei;
  const int* dstI = ei + EE;

  char* ws = (char*)d_ws;
  int*   deg    = (int*)(ws + 0);
  int*   cursor = (int*)(ws + 120064);
  float* stats  = (float*)(ws + 240128);   // cs1@0 csq1@256 cs2@512 csq2@576
  int*   rowptr = (int*)(ws + 244224);
  int*   srccsr = (int*)(ws + 364288);
  float* wae    = (float*)(ws + 2284288);
  unsigned short* W1t = (unsigned short*)(ws + 2285056);
  unsigned short* W2t = (unsigned short*)(ws + 2350592);
  float* alsrc  = (float*)(ws + 2383360);
  float* aldst  = (float*)(ws + 2863360);
  float* gateb  = (float*)(ws + 3343360);
  float* edot1  = (float*)(ws + 3463424);   // E*4 f32
  float* edot2  = (float*)(ws + 11143424);  // E f32
  unsigned short* xs1b = (unsigned short*)(ws + 13063424); // 30000*256 bf16
  unsigned short* h1b  = (unsigned short*)(ws + 28423424); // 30000*256 bf16
  unsigned short* xs2b = (unsigned short*)(ws + 43783424); // 30000*64 bf16
  float* h2     = (float*)(ws + 47623424);  // 30000*64 f32
  float* hn     = (float*)(ws + 55303424);  // 30000*64 f32

  (void)hipMemsetAsync(ws, 0, 244224, stream);   // deg, cursor, stats

  hist_kernel<<<1875, 256, 0, stream>>>(dstI, deg);
  scan_kernel<<<1, 1024, 0, stream>>>(deg, rowptr);
  prep_kernel<<<2, 256, 0, stream>>>(W1, W2, We1, ae1, We2, ae2, W1t, W2t, wae);
  edot_scatter_kernel<<<15000, 256, 0, stream>>>(ea, wae, srcI, dstI, rowptr, cursor,
                                                 srccsr, edot1, edot2);

  // ---- layer 1 (H=4) ----
  gemm1_mfma<<<235, 256, 0, stream>>>(x, W1t, as1, ad1, xs1b, alsrc, aldst);
  agg_kernel<4><<<7500, 256, 0, stream>>>(rowptr, srccsr, edot1, alsrc, aldst, xs1b, bias1, h1b, nullptr);
  bn_stats_b16_kernel<<<256, 256, 0, stream>>>(h1b, stats + 0, stats + 256);

  // ---- layer 2 (H=1) ----
  gemm2_mfma<<<235, 256, 0, stream>>>(h1b, W2t, stats + 0, stats + 256, g1, b1,
                                      as2, ad2, xs2b, alsrc, aldst);
  agg_kernel<1><<<7500, 256, 0, stream>>>(rowptr, srccsr, edot2, alsrc, aldst, xs2b, bias2, nullptr, h2);
  bn_stats_f32_kernel<<<256, 256, 0, stream>>>(h2, stats + 512, stats + 576);

  // ---- pool ----
  gate_kernel<<<7500, 256, 0, stream>>>(h2, stats + 512, stats + 576, g2, b2, Wg, bg, hn, gateb);
  pool_kernel<<<64, 256, 0, stream>>>(batch, gateb, hn, (float*)d_out);
}

// Round 6
// 364.448 us; speedup vs baseline: 1.5065x; 1.1544x over previous
//
#include <hip/hip_runtime.h>
#include <math.h>

#define NN 30000
#define EE 480000
#define BB 64

typedef __bf16 b16x8 __attribute__((ext_vector_type(8)));
typedef float  f32x4 __attribute__((ext_vector_type(4)));
typedef unsigned short u16x8 __attribute__((ext_vector_type(8)));

// ---------------- helpers ----------------
__device__ __forceinline__ float wsum64(float v){
  #pragma unroll
  for (int m = 32; m >= 1; m >>= 1) v += __shfl_xor(v, m, 64);
  return v;
}
__device__ __forceinline__ float wmax64(float v){
  #pragma unroll
  for (int m = 32; m >= 1; m >>= 1) v = fmaxf(v, __shfl_xor(v, m, 64));
  return v;
}
__device__ __forceinline__ float wsum16(float v){
  #pragma unroll
  for (int m = 1; m < 16; m <<= 1) v += __shfl_xor(v, m, 64);
  return v;
}
__device__ __forceinline__ unsigned short f2b(float f){   // fp32 -> bf16 RNE
  union { float f; unsigned u; } v; v.f = f;
  unsigned r = v.u + 0x7fffu + ((v.u >> 16) & 1u);
  return (unsigned short)(r >> 16);
}
__device__ __forceinline__ float b2f(unsigned short u){
  union { unsigned u; float f; } v; v.u = ((unsigned)u) << 16;
  return v.f;
}

// ---------------- CSR build ----------------
__global__ void hist_kernel(const int* __restrict__ dst, int* __restrict__ deg){
  int e = blockIdx.x*256 + threadIdx.x;
  if (e < EE) atomicAdd(&deg[dst[e]], 1);
}

// one-pass multi-block scan: block b sums deg[0..b*256) (redundant, coalesced, cheap)
// then LDS-scans its own 256 degrees. 118 blocks.
__global__ __launch_bounds__(256) void scan_kernel(const int* __restrict__ deg, int* __restrict__ rowptr){
  __shared__ int s[256];
  __shared__ int wred[4];
  const int b = blockIdx.x, tid = threadIdx.x;
  const int base = b*256;
  int part = 0;
  for (int idx = tid; idx < base; idx += 256) part += deg[idx];
  #pragma unroll
  for (int m = 32; m >= 1; m >>= 1) part += __shfl_xor(part, m, 64);
  if ((tid & 63) == 0) wred[tid >> 6] = part;
  __syncthreads();
  int offset = wred[0] + wred[1] + wred[2] + wred[3];
  int n = base + tid;
  int d = (n < NN) ? deg[n] : 0;
  s[tid] = d;
  __syncthreads();
  for (int off = 1; off < 256; off <<= 1){
    int v = (tid >= off) ? s[tid - off] : 0;
    __syncthreads();
    s[tid] += v;
    __syncthreads();
  }
  if (n < NN) rowptr[n] = offset + s[tid] - d;   // exclusive
  if (b == 0 && tid == 0) rowptr[NN] = EE;
}

// ---------------- prep: fully parallel W transposes (bf16) + wae dots ----------------
__global__ void prep_kernel(const float* __restrict__ W1, const float* __restrict__ W2,
                            const float* __restrict__ We1, const float* __restrict__ ae1,
                            const float* __restrict__ We2, const float* __restrict__ ae2,
                            unsigned short* __restrict__ W1t, unsigned short* __restrict__ W2t,
                            float* __restrict__ wae){
  int t = threadIdx.x, b = blockIdx.x;
  if (b < 128){
    W1t[t*128 + b] = f2b(W1[b*256 + t]);            // coalesced read of k-row b
  } else if (b < 384){
    int k = b - 128;
    if (t < 64) W2t[t*256 + k] = f2b(W2[k*64 + t]);
  } else {
    if (t < 128){
      int h = t >> 5, k = t & 31;
      float s = 0.f;
      for (int f = 0; f < 64; f++) s += We1[k*256 + h*64 + f] * ae1[h*64 + f];
      wae[h*32 + k] = s;
    } else if (t < 160){
      int k = t - 128;
      float s = 0.f;
      for (int f = 0; f < 64; f++) s += We2[k*64 + f] * ae2[f];
      wae[128 + k] = s;
    }
  }
}

// ---------------- fused edge pass: 8 lanes/edge, one 32B record per slot ----------------
// rec[slot] (8 floats): [0..3]=edot1, [4]=edot2, [5]=src(int bits), [6,7]=pad
__global__ __launch_bounds__(256) void edot_scatter_kernel(const float* __restrict__ ea,
    const float* __restrict__ wae, const int* __restrict__ src, const int* __restrict__ dst,
    const int* __restrict__ rowptr, int* __restrict__ cursor, float* __restrict__ rec){
  __shared__ float s_w[160];
  if (threadIdx.x < 160) s_w[threadIdx.x] = wae[threadIdx.x];
  __syncthreads();
  const int lane = threadIdx.x & 63;
  const int il = lane & 7;
  const int e = blockIdx.x*32 + (threadIdx.x >> 3);
  if (e >= EE) return;
  float4 v = *(const float4*)(ea + (size_t)e*32 + il*4);   // 1KB per wave, coalesced
  float dots[5];
  #pragma unroll
  for (int h = 0; h < 5; h++){
    float4 w = *(const float4*)&s_w[h*32 + il*4];
    dots[h] = v.x*w.x + v.y*w.y + v.z*w.z + v.w*w.w;
  }
  #pragma unroll
  for (int m = 1; m < 8; m <<= 1)
    #pragma unroll
    for (int h = 0; h < 5; h++) dots[h] += __shfl_xor(dots[h], m, 64);
  int slot = 0;
  if (il == 0){
    int dd = dst[e];
    slot = rowptr[dd] + atomicAdd(&cursor[dd], 1);
  }
  slot = __shfl(slot, lane & ~7, 64);                       // broadcast within 8-lane group
  if (il == 0){
    float4 lo; lo.x = dots[0]; lo.y = dots[1]; lo.z = dots[2]; lo.w = dots[3];
    *(float4*)(rec + (size_t)slot*8) = lo;
  } else if (il == 1){
    float4 hi; hi.x = dots[4]; hi.y = __int_as_float(src[e]); hi.z = 0.f; hi.w = 0.f;
    *(float4*)(rec + (size_t)slot*8 + 4) = hi;
  }
}

// ---------------- GEMM1: MFMA bf16, 128 rows, all 4 heads looped in-block ----------------
__global__ __launch_bounds__(256) void gemm1_mfma(const float* __restrict__ x,
    const unsigned short* __restrict__ Bt, const float* __restrict__ a_s, const float* __restrict__ a_d,
    unsigned short* __restrict__ out, float* __restrict__ alsrc, float* __restrict__ aldst){
  __shared__ unsigned short As[128*136];
  __shared__ unsigned short Bs[64*136];
  const int tid = threadIdx.x;
  const int w = tid >> 6, lane = tid & 63;
  const int c = lane & 15, gq = lane >> 4;
  const int m0 = blockIdx.x * 128;
  #pragma unroll
  for (int q = 0; q < 16; q++){
    int ch = tid*16 + q;
    int r = ch >> 5, off = (ch & 31)*4;
    int grow = m0 + r;
    ushort4 o;
    if (grow < NN){
      float4 v = *(const float4*)(x + (size_t)grow*128 + off);
      o.x = f2b(v.x); o.y = f2b(v.y); o.z = f2b(v.z); o.w = f2b(v.w);
    } else o = make_ushort4(0,0,0,0);
    *(ushort4*)&As[r*136 + off] = o;
  }
  #pragma unroll
  for (int q = 0; q < 4; q++){
    int ch = tid*4 + q;
    int n = ch >> 4, off = (ch & 15)*8;
    *(ulonglong2*)&Bs[n*136 + off] = *(const ulonglong2*)(Bt + (size_t)n*128 + off);
  }
  __syncthreads();
  for (int head = 0; head < 4; head++){
    f32x4 acc[2][4];
    #pragma unroll
    for (int mt = 0; mt < 2; mt++)
      #pragma unroll
      for (int nt = 0; nt < 4; nt++) acc[mt][nt] = (f32x4){0.f,0.f,0.f,0.f};
    #pragma unroll
    for (int k0 = 0; k0 < 128; k0 += 32){
      b16x8 afr[2], bfr[4];
      #pragma unroll
      for (int mt = 0; mt < 2; mt++)
        afr[mt] = *(const b16x8*)&As[(w*32 + mt*16 + c)*136 + k0 + gq*8];
      #pragma unroll
      for (int nt = 0; nt < 4; nt++)
        bfr[nt] = *(const b16x8*)&Bs[(nt*16 + c)*136 + k0 + gq*8];
      #pragma unroll
      for (int mt = 0; mt < 2; mt++)
        #pragma unroll
        for (int nt = 0; nt < 4; nt++)
          acc[mt][nt] = __builtin_amdgcn_mfma_f32_16x16x32_bf16(afr[mt], bfr[nt], acc[mt][nt], 0, 0, 0);
    }
    __syncthreads();
    if (head < 3){
      #pragma unroll
      for (int q = 0; q < 4; q++){
        int ch = tid*4 + q;
        int n = ch >> 4, off = (ch & 15)*8;
        *(ulonglong2*)&Bs[n*136 + off] = *(const ulonglong2*)(Bt + (size_t)((head+1)*64 + n)*128 + off);
      }
    }
    float asv[4], adv[4];
    #pragma unroll
    for (int nt = 0; nt < 4; nt++){
      asv[nt] = a_s[head*64 + nt*16 + c];
      adv[nt] = a_d[head*64 + nt*16 + c];
    }
    #pragma unroll
    for (int mt = 0; mt < 2; mt++){
      int base_row = m0 + w*32 + mt*16 + gq*4;
      #pragma unroll
      for (int r = 0; r < 4; r++){
        int row = base_row + r;
        float ps = 0.f, pd = 0.f;
        #pragma unroll
        for (int nt = 0; nt < 4; nt++){
          ps += acc[mt][nt][r] * asv[nt];
          pd += acc[mt][nt][r] * adv[nt];
        }
        ps = wsum16(ps); pd = wsum16(pd);
        if (row < NN){
          if (c == 0){
            alsrc[(size_t)row*4 + head] = ps;
            aldst[(size_t)row*4 + head] = pd;
          }
          #pragma unroll
          for (int nt = 0; nt < 4; nt++)
            out[(size_t)row*256 + head*64 + nt*16 + c] = f2b(acc[mt][nt][r]);
        }
      }
    }
    if (head < 3) __syncthreads();
  }
}

// ---------------- GEMM2: MFMA bf16, BN(from raw stats)+ReLU fused on A ----------------
__global__ __launch_bounds__(256) void gemm2_mfma(const unsigned short* __restrict__ Ab,
    const unsigned short* __restrict__ Bt,
    const float* __restrict__ cs, const float* __restrict__ csq,
    const float* __restrict__ g, const float* __restrict__ b,
    const float* __restrict__ a_s, const float* __restrict__ a_d,
    unsigned short* __restrict__ out, float* __restrict__ alsrc, float* __restrict__ aldst){
  __shared__ unsigned short As[128*136];
  __shared__ unsigned short Bs[64*136];
  __shared__ float s_scale[256], s_shift[256];
  const int tid = threadIdx.x;
  const int w = tid >> 6, lane = tid & 63;
  const int c = lane & 15, gq = lane >> 4;
  const int m0 = blockIdx.x * 128;
  if (tid < 256){
    float mu  = cs[tid]  * (1.f/NN);
    float var = csq[tid] * (1.f/NN) - mu*mu;
    float rs  = rsqrtf(var + 1e-5f);
    float sc  = rs * g[tid];
    s_scale[tid] = sc;
    s_shift[tid] = b[tid] - mu*sc;
  }
  __syncthreads();
  f32x4 acc[2][4];
  #pragma unroll
  for (int mt = 0; mt < 2; mt++)
    #pragma unroll
    for (int nt = 0; nt < 4; nt++) acc[mt][nt] = (f32x4){0.f,0.f,0.f,0.f};
  for (int kp = 0; kp < 256; kp += 128){
    #pragma unroll
    for (int q = 0; q < 16; q++){
      int ch = tid*16 + q;
      int r = ch >> 5, off = (ch & 31)*4;
      int grow = m0 + r;
      ushort4 o;
      if (grow < NN){
        ushort4 v = *(const ushort4*)(Ab + (size_t)grow*256 + kp + off);
        float4 sc = *(const float4*)&s_scale[kp + off];
        float4 sh = *(const float4*)&s_shift[kp + off];
        o.x = f2b(fmaxf(fmaf(b2f(v.x), sc.x, sh.x), 0.f));
        o.y = f2b(fmaxf(fmaf(b2f(v.y), sc.y, sh.y), 0.f));
        o.z = f2b(fmaxf(fmaf(b2f(v.z), sc.z, sh.z), 0.f));
        o.w = f2b(fmaxf(fmaf(b2f(v.w), sc.w, sh.w), 0.f));
      } else o = make_ushort4(0,0,0,0);
      *(ushort4*)&As[r*136 + off] = o;
    }
    #pragma unroll
    for (int q = 0; q < 4; q++){
      int ch = tid*4 + q;
      int n = ch >> 4, off = (ch & 15)*8;
      *(ulonglong2*)&Bs[n*136 + off] = *(const ulonglong2*)(Bt + (size_t)n*256 + kp + off);
    }
    __syncthreads();
    #pragma unroll
    for (int k0 = 0; k0 < 128; k0 += 32){
      b16x8 afr[2], bfr[4];
      #pragma unroll
      for (int mt = 0; mt < 2; mt++)
        afr[mt] = *(const b16x8*)&As[(w*32 + mt*16 + c)*136 + k0 + gq*8];
      #pragma unroll
      for (int nt = 0; nt < 4; nt++)
        bfr[nt] = *(const b16x8*)&Bs[(nt*16 + c)*136 + k0 + gq*8];
      #pragma unroll
      for (int mt = 0; mt < 2; mt++)
        #pragma unroll
        for (int nt = 0; nt < 4; nt++)
          acc[mt][nt] = __builtin_amdgcn_mfma_f32_16x16x32_bf16(afr[mt], bfr[nt], acc[mt][nt], 0, 0, 0);
    }
    __syncthreads();
  }
  float asv[4], adv[4];
  #pragma unroll
  for (int nt = 0; nt < 4; nt++){
    asv[nt] = a_s[nt*16 + c];
    adv[nt] = a_d[nt*16 + c];
  }
  #pragma unroll
  for (int mt = 0; mt < 2; mt++){
    int base_row = m0 + w*32 + mt*16 + gq*4;
    #pragma unroll
    for (int r = 0; r < 4; r++){
      int row = base_row + r;
      float ps = 0.f, pd = 0.f;
      #pragma unroll
      for (int nt = 0; nt < 4; nt++){
        ps += acc[mt][nt][r] * asv[nt];
        pd += acc[mt][nt][r] * adv[nt];
      }
      ps = wsum16(ps); pd = wsum16(pd);
      if (row < NN){
        if (c == 0){
          alsrc[row] = ps;
          aldst[row] = pd;
        }
        #pragma unroll
        for (int nt = 0; nt < 4; nt++)
          out[(size_t)row*64 + nt*16 + c] = f2b(acc[mt][nt][r]);
      }
    }
  }
}

// ---------------- segment softmax + wide bf16 gather, 32B-record edges ----------------
template<int H>
__global__ __launch_bounds__(256) void agg_kernel(const int* __restrict__ rowptr,
    const float* __restrict__ rec,
    const float* __restrict__ al_src, const float* __restrict__ al_dst,
    const unsigned short* __restrict__ xsb, const float* __restrict__ bias,
    unsigned short* __restrict__ outb, float* __restrict__ outf){
  constexpr int CH = 128;
  __shared__ float s_e_all[4][CH*H];
  __shared__ int   s_src_all[4][CH];
  const int wid  = threadIdx.x >> 6;
  const int lane = threadIdx.x & 63;
  const int i = blockIdx.x*4 + wid;
  float* s_e  = s_e_all[wid];
  int*   s_src = s_src_all[wid];
  const int r0 = rowptr[i];
  const int d  = rowptr[i+1] - r0;
  float ad[H], asi[H];
  #pragma unroll
  for (int h = 0; h < H; h++){ ad[h] = al_dst[(size_t)i*H+h]; asi[h] = al_src[(size_t)i*H+h]; }
  float sesum[H], m[H];
  #pragma unroll
  for (int h = 0; h < H; h++){ sesum[h] = 0.f; m[h] = -1e30f; }
  for (int t = lane; t < d; t += 64){
    const float* rp = rec + (size_t)(r0 + t)*8;
    float al[H];
    int sn;
    if constexpr (H == 4){
      float4 ev = *(const float4*)rp;
      float2 hi = *(const float2*)(rp + 4);
      sn = __float_as_int(hi.y);
      float4 av = *(const float4*)(al_src + (size_t)sn*4);
      al[0]=av.x+ad[0]+ev.x; al[1]=av.y+ad[1]+ev.y; al[2]=av.z+ad[2]+ev.z; al[3]=av.w+ad[3]+ev.w;
      sesum[0]+=ev.x; sesum[1]+=ev.y; sesum[2]+=ev.z; sesum[3]+=ev.w;
    } else {
      float2 hi = *(const float2*)(rp + 4);
      sn = __float_as_int(hi.y);
      al[0] = al_src[sn] + ad[0] + hi.x;
      sesum[0] += hi.x;
    }
    if (t < CH) s_src[t] = sn;
    #pragma unroll
    for (int h = 0; h < H; h++){
      float a = al[h]; a = a > 0.f ? a : 0.2f*a;
      if (t < CH) s_e[t*H+h] = a;
      m[h] = fmaxf(m[h], a);
    }
  }
  float invd = (d > 0) ? 1.f/(float)d : 0.f;
  float sa[H];
  #pragma unroll
  for (int h = 0; h < H; h++){
    sesum[h] = wsum64(sesum[h]);
    m[h] = wmax64(m[h]);
    float a = asi[h] + ad[h] + sesum[h]*invd;
    sa[h] = a > 0.f ? a : 0.2f*a;
    m[h] = fmaxf(m[h], sa[h]);
  }
  float acc8[8];
  #pragma unroll
  for (int j = 0; j < 8; j++) acc8[j] = 0.f;
  float dpart[H];
  #pragma unroll
  for (int h = 0; h < H; h++) dpart[h] = 0.f;
  const int half = lane >> 5, il5 = lane & 31;   // H==4 mapping
  const int grp  = lane >> 3, il3 = lane & 7;    // H==1 mapping
  int c0 = 0;
  while (c0 < d){
    int cl = min(CH, d - c0);
    if (c0 > 0){
      for (int t = lane; t < cl; t += 64){
        const float* rp = rec + (size_t)(r0 + c0 + t)*8;
        if constexpr (H == 4){
          float4 ev = *(const float4*)rp;
          float2 hi = *(const float2*)(rp + 4);
          int sn = __float_as_int(hi.y);
          s_src[t] = sn;
          float4 av = *(const float4*)(al_src + (size_t)sn*4);
          float a0=av.x+ad[0]+ev.x, a1=av.y+ad[1]+ev.y, a2=av.z+ad[2]+ev.z, a3=av.w+ad[3]+ev.w;
          s_e[t*4+0]=a0>0.f?a0:0.2f*a0; s_e[t*4+1]=a1>0.f?a1:0.2f*a1;
          s_e[t*4+2]=a2>0.f?a2:0.2f*a2; s_e[t*4+3]=a3>0.f?a3:0.2f*a3;
        } else {
          float2 hi = *(const float2*)(rp + 4);
          int sn = __float_as_int(hi.y);
          s_src[t] = sn;
          float a = al_src[sn] + ad[0] + hi.x;
          s_e[t] = a > 0.f ? a : 0.2f*a;
        }
      }
    }
    for (int t = lane; t < cl; t += 64){
      #pragma unroll
      for (int h = 0; h < H; h++){
        float e = __expf(s_e[t*H+h] - m[h]);
        s_e[t*H+h] = e;
        dpart[h] += e;
      }
    }
    __builtin_amdgcn_wave_barrier();
    if constexpr (H == 4){
      const int hd = il5 >> 3;
      for (int t = half; t < cl; t += 2){
        int sn = s_src[t];
        float wv = s_e[t*4 + hd];
        u16x8 u = *(const u16x8*)(xsb + (size_t)sn*256 + il5*8);
        #pragma unroll
        for (int j = 0; j < 8; j++) acc8[j] += wv * b2f(u[j]);
      }
    } else {
      for (int t = grp; t < cl; t += 8){
        int sn = s_src[t];
        float wv = s_e[t];
        u16x8 u = *(const u16x8*)(xsb + (size_t)sn*64 + il3*8);
        #pragma unroll
        for (int j = 0; j < 8; j++) acc8[j] += wv * b2f(u[j]);
      }
    }
    __builtin_amdgcn_wave_barrier();
    c0 += CH;
  }
  float es[H];
  #pragma unroll
  for (int h = 0; h < H; h++) es[h] = __expf(sa[h] - m[h]);
  if (lane == 0){
    #pragma unroll
    for (int h = 0; h < H; h++) dpart[h] += es[h];
  }
  if constexpr (H == 4){
    if (half == 0){
      float wv = es[il5 >> 3];
      u16x8 u = *(const u16x8*)(xsb + (size_t)i*256 + il5*8);
      #pragma unroll
      for (int j = 0; j < 8; j++) acc8[j] += wv * b2f(u[j]);
    }
  } else {
    if (grp == 0){
      float wv = es[0];
      u16x8 u = *(const u16x8*)(xsb + (size_t)i*64 + il3*8);
      #pragma unroll
      for (int j = 0; j < 8; j++) acc8[j] += wv * b2f(u[j]);
    }
  }
  float denom[H];
  #pragma unroll
  for (int h = 0; h < H; h++) denom[h] = wsum64(dpart[h]);
  if constexpr (H == 4){
    #pragma unroll
    for (int j = 0; j < 8; j++) acc8[j] += __shfl_xor(acc8[j], 32, 64);
    if (lane < 32){
      float inv = 1.f / denom[il5 >> 3];
      u16x8 o;
      #pragma unroll
      for (int j = 0; j < 8; j++) o[j] = f2b(acc8[j]*inv + bias[il5*8 + j]);
      *(u16x8*)(outb + (size_t)i*256 + il5*8) = o;
    }
  } else {
    #pragma unroll
    for (int j = 0; j < 8; j++){
      acc8[j] += __shfl_xor(acc8[j], 8, 64);
      acc8[j] += __shfl_xor(acc8[j], 16, 64);
      acc8[j] += __shfl_xor(acc8[j], 32, 64);
    }
    if (lane < 8){
      float inv = 1.f / denom[0];
      float4 o0, o1;
      o0.x = acc8[0]*inv + bias[il3*8+0]; o0.y = acc8[1]*inv + bias[il3*8+1];
      o0.z = acc8[2]*inv + bias[il3*8+2]; o0.w = acc8[3]*inv + bias[il3*8+3];
      o1.x = acc8[4]*inv + bias[il3*8+4]; o1.y = acc8[5]*inv + bias[il3*8+5];
      o1.z = acc8[6]*inv + bias[il3*8+6]; o1.w = acc8[7]*inv + bias[il3*8+7];
      *(float4*)(outf + (size_t)i*64 + il3*8)     = o0;
      *(float4*)(outf + (size_t)i*64 + il3*8 + 4) = o1;
    }
  }
}

// ---------------- BN stats ----------------
__global__ __launch_bounds__(256) void bn_stats_b16_kernel(const unsigned short* __restrict__ h,
    float* __restrict__ cs, float* __restrict__ csq){
  __shared__ float s_red[4][256], q_red[4][256];
  const int tid = threadIdx.x;
  const int wv = tid >> 6, lane = tid & 63;
  const int rg = lane >> 5, cg = lane & 31;
  float s8[8], q8[8];
  #pragma unroll
  for (int j = 0; j < 8; j++){ s8[j] = 0.f; q8[j] = 0.f; }
  for (int chunk = blockIdx.x; chunk < 3750; chunk += 256){
    int r = chunk*8 + wv*2 + rg;
    u16x8 u = *(const u16x8*)(h + (size_t)r*256 + cg*8);
    #pragma unroll
    for (int j = 0; j < 8; j++){
      float v = b2f(u[j]);
      s8[j] += v; q8[j] += v*v;
    }
  }
  #pragma unroll
  for (int j = 0; j < 8; j++){
    s8[j] += __shfl_xor(s8[j], 32, 64);
    q8[j] += __shfl_xor(q8[j], 32, 64);
  }
  if (lane < 32){
    #pragma unroll
    for (int j = 0; j < 8; j++){
      s_red[wv][cg*8 + j] = s8[j];
      q_red[wv][cg*8 + j] = q8[j];
    }
  }
  __syncthreads();
  if (tid < 256){
    float ts = s_red[0][tid] + s_red[1][tid] + s_red[2][tid] + s_red[3][tid];
    float tq = q_red[0][tid] + q_red[1][tid] + q_red[2][tid] + q_red[3][tid];
    atomicAdd(&cs[tid], ts);
    atomicAdd(&csq[tid], tq);
  }
}

__global__ __launch_bounds__(256) void bn_stats_f32_kernel(const float* __restrict__ h,
    float* __restrict__ cs, float* __restrict__ csq){
  int col = threadIdx.x & 63;
  int ro  = threadIdx.x >> 6;
  float s = 0.f, s2 = 0.f;
  for (int r = blockIdx.x*4 + ro; r < NN; r += 1024){
    float v = h[(size_t)r*64 + col];
    s += v; s2 += v*v;
  }
  atomicAdd(&cs[col], s);
  atomicAdd(&csq[col], s2);
}

// ---------------- pooling ----------------
__global__ __launch_bounds__(256) void gate_kernel(const float* __restrict__ h,
    const float* __restrict__ cs, const float* __restrict__ csq,
    const float* __restrict__ g2, const float* __restrict__ b2,
    const float* __restrict__ Wg, const float* __restrict__ bg,
    float* __restrict__ hn, float* __restrict__ gate){
  int wid = threadIdx.x >> 6, lane = threadIdx.x & 63;
  int n = blockIdx.x*4 + wid;
  float mu  = cs[lane]  * (1.f/NN);
  float var = csq[lane] * (1.f/NN) - mu*mu;
  float rs  = rsqrtf(var + 1e-5f);
  float sc  = rs * g2[lane];
  float sh  = b2[lane] - mu*sc;
  float v = h[(size_t)n*64 + lane];
  float xx = fmaxf(fmaf(v, sc, sh), 0.f);
  hn[(size_t)n*64 + lane] = xx;
  float p = wsum64(xx * Wg[lane]);
  if (lane == 0) gate[n] = p + bg[0];
}

__global__ __launch_bounds__(256) void pool_kernel(const int* __restrict__ batch,
    const float* __restrict__ gate, const float* __restrict__ hn, float* __restrict__ out){
  __shared__ float red[256];
  __shared__ float a_red[4][64], w_red[4];
  __shared__ int seb[2];
  int b = blockIdx.x, tid = threadIdx.x;
  int wv = tid >> 6, lane = tid & 63;
  if (tid < 2){
    int target = b + tid;
    int lo = 0, hi = NN;
    while (lo < hi){ int mid = (lo+hi) >> 1; if (batch[mid] < target) lo = mid+1; else hi = mid; }
    seb[tid] = lo;
  }
  __syncthreads();
  int s = seb[0], e = seb[1];
  if (e <= s){ if (tid < 64) out[b*64 + tid] = 0.f; return; }
  float mloc = -1e30f;
  for (int n = s + tid; n < e; n += 256) mloc = fmaxf(mloc, gate[n]);
  mloc = wmax64(mloc);
  if (lane == 0) red[wv] = mloc;
  __syncthreads();
  float m = fmaxf(fmaxf(red[0], red[1]), fmaxf(red[2], red[3]));
  int rgrp = tid >> 4, cq = tid & 15;
  f32x4 acc = (f32x4){0.f,0.f,0.f,0.f};
  float wp = 0.f;
  for (int n = s + rgrp; n < e; n += 16){
    float wgt = __expf(gate[n] - m);
    float4 v = *(const float4*)(hn + (size_t)n*64 + cq*4);
    acc[0] += wgt*v.x; acc[1] += wgt*v.y; acc[2] += wgt*v.z; acc[3] += wgt*v.w;
    if (cq == 0) wp += wgt;
  }
  #pragma unroll
  for (int j = 0; j < 4; j++){
    acc[j] += __shfl_xor(acc[j], 16, 64);
    acc[j] += __shfl_xor(acc[j], 32, 64);
  }
  wp += __shfl_xor(wp, 16, 64);
  wp += __shfl_xor(wp, 32, 64);
  if (lane < 16){
    #pragma unroll
    for (int j = 0; j < 4; j++) a_red[wv][lane*4 + j] = acc[j];
  }
  if (lane == 0) w_red[wv] = wp;
  __syncthreads();
  if (tid < 64){
    float tot = a_red[0][tid] + a_red[1][tid] + a_red[2][tid] + a_red[3][tid];
    float wsm = w_red[0] + w_red[1] + w_red[2] + w_red[3];
    out[b*64 + tid] = tot / wsm;
  }
}

// ---------------- host ----------------
extern "C" void kernel_launch(void* const* d_in, const int* in_sizes, int n_in,
                              void* d_out, int out_size, void* d_ws, size_t ws_size,
                              hipStream_t stream){
  const float* x     = (const float*)d_in[0];
  const float* ea    = (const float*)d_in[1];
  const int*   ei    = (const int*)d_in[2];
  const int*   batch = (const int*)d_in[3];
  const float* W1    = (const float*)d_in[4];
  const float* We1   = (const float*)d_in[5];
  const float* as1   = (const float*)d_in[6];
  const float* ad1   = (const float*)d_in[7];
  const float* ae1   = (const float*)d_in[8];
  const float* bias1 = (const float*)d_in[9];
  const float* g1    = (const float*)d_in[10];
  const float* b1    = (const float*)d_in[11];
  const float* W2    = (const float*)d_in[12];
  const float* We2   = (const float*)d_in[13];
  const float* as2   = (const float*)d_in[14];
  const float* ad2   = (const float*)d_in[15];
  const float* ae2   = (const float*)d_in[16];
  const float* bias2 = (const float*)d_in[17];
  const float* g2    = (const float*)d_in[18];
  const float* b2    = (const float*)d_in[19];
  const float* Wg    = (const float*)d_in[20];
  const float* bg    = (const float*)d_in[21];
  const int* srcI = ei;
  const int* dstI = ei + EE;

  char* ws = (char*)d_ws;
  int*   deg    = (int*)(ws + 0);
  int*   cursor = (int*)(ws + 120064);
  float* stats  = (float*)(ws + 240128);   // cs1@0 csq1@256 cs2@512 csq2@576
  int*   rowptr = (int*)(ws + 244224);
  float* wae    = (float*)(ws + 364288);
  unsigned short* W1t = (unsigned short*)(ws + 365056);
  unsigned short* W2t = (unsigned short*)(ws + 430592);
  float* alsrc  = (float*)(ws + 463360);
  float* aldst  = (float*)(ws + 943360);
  float* gateb  = (float*)(ws + 1423360);
  float* rec    = (float*)(ws + 1543424);   // E * 32B records
  unsigned short* xs1b = (unsigned short*)(ws + 16903424); // 30000*256 bf16
  unsigned short* h1b  = (unsigned short*)(ws + 32263424); // 30000*256 bf16
  unsigned short* xs2b = (unsigned short*)(ws + 47623424); // 30000*64 bf16
  float* h2     = (float*)(ws + 51463424);  // 30000*64 f32
  float* hn     = (float*)(ws + 59143424);  // 30000*64 f32
  // total ~66.8 MB

  (void)hipMemsetAsync(ws, 0, 244224, stream);   // deg, cursor, stats

  hist_kernel<<<1875, 256, 0, stream>>>(dstI, deg);
  scan_kernel<<<118, 256, 0, stream>>>(deg, rowptr);
  prep_kernel<<<385, 256, 0, stream>>>(W1, W2, We1, ae1, We2, ae2, W1t, W2t, wae);
  edot_scatter_kernel<<<15000, 256, 0, stream>>>(ea, wae, srcI, dstI, rowptr, cursor, rec);

  // ---- layer 1 (H=4) ----
  gemm1_mfma<<<235, 256, 0, stream>>>(x, W1t, as1, ad1, xs1b, alsrc, aldst);
  agg_kernel<4><<<7500, 256, 0, stream>>>(rowptr, rec, alsrc, aldst, xs1b, bias1, h1b, nullptr);
  bn_stats_b16_kernel<<<256, 256, 0, stream>>>(h1b, stats + 0, stats + 256);

  // ---- layer 2 (H=1) ----
  gemm2_mfma<<<235, 256, 0, stream>>>(h1b, W2t, stats + 0, stats + 256, g1, b1,
                                      as2, ad2, xs2b, alsrc, aldst);
  agg_kernel<1><<<7500, 256, 0, stream>>>(rowptr, rec, alsrc, aldst, xs2b, bias2, nullptr, h2);
  bn_stats_f32_kernel<<<256, 256, 0, stream>>>(h2, stats + 512, stats + 576);

  // ---- pool ----
  gate_kernel<<<7500, 256, 0, stream>>>(h2, stats + 512, stats + 576, g2, b2, Wg, bg, hn, gateb);
  pool_kernel<<<64, 256, 0, stream>>>(batch, gateb, hn, (float*)d_out);
}